// Round 1
// baseline (1547.899 us; speedup 1.0000x reference)
//
#include <hip/hip_runtime.h>
#include <hip/hip_bf16.h>

typedef __attribute__((ext_vector_type(8))) short short8;
typedef __attribute__((ext_vector_type(4))) short short4v;
typedef __attribute__((ext_vector_type(4))) float f32x4;

__device__ __forceinline__ unsigned short f2bf(float f) {
  unsigned u = __builtin_bit_cast(unsigned, f);
  u += 0x7FFFu + ((u >> 16) & 1u);
  return (unsigned short)(u >> 16);
}
__device__ __forceinline__ float bf2f(unsigned short b) {
  unsigned u = ((unsigned)b) << 16;
  return __builtin_bit_cast(float, u);
}

// ---------------------------------------------------------------------------
// U tables: U_nodetype[j*128+k], j = r*4+h. For agent: r even -> att_src side,
// r odd -> att_dst side (agent is src of r0,r2 and dst of r1,r3). Track: swapped.
__global__ void prep_u(const float* __restrict__ W, const float* __restrict__ att_src,
                       const float* __restrict__ att_dst,
                       float* __restrict__ U_agent, float* __restrict__ U_track) {
  int idx = blockIdx.x * 256 + threadIdx.x;
  if (idx >= 2 * 16 * 128) return;
  int which = idx >> 11;           // 0 agent, 1 track
  int rem = idx & 2047;
  int j = rem >> 7;                // 0..15
  int k = rem & 127;
  int r = j >> 2, h = j & 3;
  bool srcSide = (which == 0) ? ((r & 1) == 0) : ((r & 1) == 1);
  const float* att = (srcSide ? att_src : att_dst) + (r * 4 + h) * 64;
  const float* Wr = W + (r * 128 + k) * 256 + h * 64;
  float s = 0.f;
#pragma unroll 8
  for (int c = 0; c < 64; ++c) s += Wr[c] * att[c];
  (which ? U_track : U_agent)[j * 128 + k] = s;
}

// Wt[r][c][k] = bf16(W[r][k][c])  (transposed, bf16)
__global__ void prep_wt(const float* __restrict__ W, unsigned short* __restrict__ Wt) {
  int idx = blockIdx.x * 256 + threadIdx.x;
  if (idx >= 4 * 256 * 128) return;
  int r = idx >> 15;
  int rem = idx & 32767;
  int c = rem >> 7;
  int k = rem & 127;
  Wt[idx] = f2bf(W[(r * 128 + k) * 256 + c]);
}

// One wave per node: computes 16 logit dots (4 relations x 4 heads) in one x pass.
__global__ void node_al(const float* __restrict__ x, const float* __restrict__ U, int N,
                        float* __restrict__ d0, float* __restrict__ d1,
                        float* __restrict__ d2, float* __restrict__ d3) {
  __shared__ float Ul[16 * 128];
  int tid = threadIdx.x;
  for (int i = tid; i < 2048; i += 256) Ul[i] = U[i];
  __syncthreads();
  int node = (blockIdx.x * 256 + tid) >> 6;
  int lane = tid & 63;
  if (node >= N) return;
  float2 xv = *(const float2*)(x + node * 128 + lane * 2);
  float p[16];
#pragma unroll
  for (int j = 0; j < 16; ++j) {
    float2 uv = *(const float2*)(&Ul[j * 128 + lane * 2]);
    p[j] = xv.x * uv.x + xv.y * uv.y;
  }
#pragma unroll
  for (int m = 32; m >= 1; m >>= 1) {
#pragma unroll
    for (int j = 0; j < 16; ++j) p[j] += __shfl_xor(p[j], m);
  }
  if (lane == 0) {
    float* dsts[4] = {d0, d1, d2, d3};
#pragma unroll
    for (int r = 0; r < 4; ++r) {
      float4 v = make_float4(p[r * 4], p[r * 4 + 1], p[r * 4 + 2], p[r * 4 + 3]);
      *(float4*)(dsts[r] + node * 4) = v;
    }
  }
}

// out init: 0.5*(bias_a + bias_b) everywhere (also overwrites 0xAA poison)
__global__ void init_out(float* __restrict__ out, const float* __restrict__ bias,
                         int NA, int NT) {
  int idx = blockIdx.x * 256 + threadIdx.x;   // one float4 per thread
  int total4 = (NA + NT) * 16;
  if (idx >= total4) return;
  int f = idx * 4;
  int c = f & 63;
  const float *b0, *b1;
  if (f < NA * 64) { b0 = bias + 64; b1 = bias + 192; }   // agent: rel 1,3
  else             { b0 = bias;      b1 = bias + 128; }   // track: rel 0,2
  float4 v;
  v.x = 0.5f * (b0[c] + b1[c]);
  v.y = 0.5f * (b0[c + 1] + b1[c + 1]);
  v.z = 0.5f * (b0[c + 2] + b1[c + 2]);
  v.w = 0.5f * (b0[c + 3] + b1[c + 3]);
  *(float4*)(out + f) = v;
}

// P = bf16(X @ W[r]) : [Ns][256], MFMA 16x16x32 bf16, block = 64 rows x 128 cols
__global__ __launch_bounds__(256) void proj_gemm(const float* __restrict__ X,
                                                 const unsigned short* __restrict__ Wt,
                                                 unsigned short* __restrict__ P, int Ns) {
  __shared__ unsigned short Xs[64 * 136];
  __shared__ unsigned short Ws[128 * 136];
  int tid = threadIdx.x;
  int m0 = blockIdx.x * 64;
  int cs = blockIdx.y * 128;
  // stage X (f32 -> bf16), rows m0..m0+63, k 0..127
#pragma unroll
  for (int it = 0; it < 8; ++it) {
    int idx = (tid + it * 256) * 4;
    int row = idx >> 7, k = idx & 127;
    int g = m0 + row;
    float4 v = make_float4(0.f, 0.f, 0.f, 0.f);
    if (g < Ns) v = *(const float4*)(X + g * 128 + k);
    short4v sv;
    sv.x = (short)f2bf(v.x); sv.y = (short)f2bf(v.y);
    sv.z = (short)f2bf(v.z); sv.w = (short)f2bf(v.w);
    *(short4v*)&Xs[row * 136 + k] = sv;
  }
  // stage Wt rows (= output cols) cs..cs+127
#pragma unroll
  for (int it = 0; it < 8; ++it) {
    int idx = (tid + it * 256) * 8;
    int row = idx >> 7, k = idx & 127;
    short8 v = *(const short8*)(Wt + (cs + row) * 128 + k);
    *(short8*)&Ws[row * 136 + k] = v;
  }
  __syncthreads();
  int lane = tid & 63, w = tid >> 6;
  f32x4 acc[8];
#pragma unroll
  for (int t = 0; t < 8; ++t) acc[t] = (f32x4){0.f, 0.f, 0.f, 0.f};
  int aoff = (w * 16 + (lane & 15)) * 136 + (lane >> 4) * 8;
  int boff = (lane & 15) * 136 + (lane >> 4) * 8;
#pragma unroll
  for (int kc = 0; kc < 4; ++kc) {
    short8 a = *(const short8*)&Xs[aoff + kc * 32];
#pragma unroll
    for (int t = 0; t < 8; ++t) {
      short8 b = *(const short8*)&Ws[boff + t * 16 * 136 + kc * 32];
      acc[t] = __builtin_amdgcn_mfma_f32_16x16x32_bf16(a, b, acc[t], 0, 0, 0);
    }
  }
#pragma unroll
  for (int t = 0; t < 8; ++t) {
#pragma unroll
    for (int q = 0; q < 4; ++q) {
      int grow = m0 + w * 16 + (lane >> 4) * 4 + q;
      if (grow < Ns) P[grow * 256 + cs + t * 16 + (lane & 15)] = f2bf(acc[t][q]);
    }
  }
}

// pass A: segsum[d][h] += exp(leaky(alS[s]+alD[d]))
__global__ void edge_passA(const int* __restrict__ esrc, const int* __restrict__ edst,
                           const float* __restrict__ alS, const float* __restrict__ alD,
                           float* __restrict__ seg, int E) {
  int e = blockIdx.x * 256 + threadIdx.x;
  if (e >= E) return;
  int s = esrc[e], d = edst[e];
  float4 as = *(const float4*)(alS + s * 4);
  float4 ad = *(const float4*)(alD + d * 4);
  float v0 = as.x + ad.x, v1 = as.y + ad.y, v2 = as.z + ad.z, v3 = as.w + ad.w;
  v0 = v0 > 0.f ? v0 : 0.2f * v0;
  v1 = v1 > 0.f ? v1 : 0.2f * v1;
  v2 = v2 > 0.f ? v2 : 0.2f * v2;
  v3 = v3 > 0.f ? v3 : 0.2f * v3;
  unsafeAtomicAdd(seg + d * 4 + 0, __expf(v0));
  unsafeAtomicAdd(seg + d * 4 + 1, __expf(v1));
  unsafeAtomicAdd(seg + d * 4 + 2, __expf(v2));
  unsafeAtomicAdd(seg + d * 4 + 3, __expf(v3));
}

// pass B: one wave per edge; out[d][c] += 0.125 * sum_h alpha_h * P[s][h*64+c]
__global__ void edge_passB(const int* __restrict__ esrc, const int* __restrict__ edst,
                           const float* __restrict__ alS, const float* __restrict__ alD,
                           const float* __restrict__ seg, const unsigned short* __restrict__ P,
                           float* __restrict__ outp, int E) {
  int gt = blockIdx.x * 256 + threadIdx.x;
  int e = gt >> 6;
  if (e >= E) return;
  int lane = threadIdx.x & 63;
  int s = esrc[e], d = edst[e];
  int h = lane >> 4;
  float sc = alS[s * 4 + h] + alD[d * 4 + h];
  sc = sc > 0.f ? sc : 0.2f * sc;
  float alpha = __expf(sc) / (seg[d * 4 + h] + 1e-16f);
  short4v pv = *(const short4v*)(P + s * 256 + lane * 4);
  float a0 = alpha * bf2f((unsigned short)pv.x);
  float a1 = alpha * bf2f((unsigned short)pv.y);
  float a2 = alpha * bf2f((unsigned short)pv.z);
  float a3 = alpha * bf2f((unsigned short)pv.w);
  a0 += __shfl_xor(a0, 16); a0 += __shfl_xor(a0, 32);
  a1 += __shfl_xor(a1, 16); a1 += __shfl_xor(a1, 32);
  a2 += __shfl_xor(a2, 16); a2 += __shfl_xor(a2, 32);
  a3 += __shfl_xor(a3, 16); a3 += __shfl_xor(a3, 32);
  float val = (h == 0) ? a0 : (h == 1) ? a1 : (h == 2) ? a2 : a3;
  unsafeAtomicAdd(outp + d * 64 + (lane & 15) * 4 + h, 0.125f * val);
}

extern "C" void kernel_launch(void* const* d_in, const int* in_sizes, int n_in,
                              void* d_out, int out_size, void* d_ws, size_t ws_size,
                              hipStream_t stream) {
  const float* x_agent = (const float*)d_in[0];
  const float* x_track = (const float*)d_in[1];
  const float* W = (const float*)d_in[2];
  const float* att_src = (const float*)d_in[3];
  const float* att_dst = (const float*)d_in[4];
  const float* bias = (const float*)d_in[5];
  const int* es[4] = {(const int*)d_in[6], (const int*)d_in[8],
                      (const int*)d_in[10], (const int*)d_in[12]};
  const int* ed[4] = {(const int*)d_in[7], (const int*)d_in[9],
                      (const int*)d_in[11], (const int*)d_in[13]};
  int NA = in_sizes[0] / 128;
  int NT = in_sizes[1] / 128;
  float* out = (float*)d_out;

  int Ns[4] = {NA, NT, NA, NT};
  int Nd[4] = {NT, NA, NT, NA};
  const float* xsrc[4] = {x_agent, x_track, x_agent, x_track};

  char* ws = (char*)d_ws;
  size_t off = 0;
  auto alloc = [&](size_t bytes) -> void* {
    void* p = ws + off;
    off += (bytes + 255) & ~(size_t)255;
    return p;
  };
  int maxN = NA > NT ? NA : NT;
  unsigned short* P = (unsigned short*)alloc((size_t)maxN * 256 * 2);
  float *alS[4], *alD[4], *seg[4];
  for (int r = 0; r < 4; ++r) alS[r] = (float*)alloc((size_t)Ns[r] * 4 * 4);
  for (int r = 0; r < 4; ++r) alD[r] = (float*)alloc((size_t)Nd[r] * 4 * 4);
  for (int r = 0; r < 4; ++r) seg[r] = (float*)alloc((size_t)Nd[r] * 4 * 4);
  float* U_agent = (float*)alloc(16 * 128 * 4);
  float* U_track = (float*)alloc(16 * 128 * 4);
  unsigned short* Wt = (unsigned short*)alloc(4 * 256 * 128 * 2);

  prep_u<<<16, 256, 0, stream>>>(W, att_src, att_dst, U_agent, U_track);
  prep_wt<<<512, 256, 0, stream>>>(W, Wt);

  node_al<<<(NA + 3) / 4, 256, 0, stream>>>(x_agent, U_agent, NA,
                                            alS[0], alD[1], alS[2], alD[3]);
  node_al<<<(NT + 3) / 4, 256, 0, stream>>>(x_track, U_track, NT,
                                            alD[0], alS[1], alD[2], alS[3]);
  for (int r = 0; r < 4; ++r)
    hipMemsetAsync(seg[r], 0, (size_t)Nd[r] * 4 * 4, stream);

  int total4 = (NA + NT) * 16;
  init_out<<<(total4 + 255) / 256, 256, 0, stream>>>(out, bias, NA, NT);

  for (int r = 0; r < 4; ++r) {
    int E = in_sizes[6 + 2 * r];
    dim3 pg((Ns[r] + 63) / 64, 2);
    proj_gemm<<<pg, 256, 0, stream>>>(xsrc[r], Wt + r * 256 * 128, P, Ns[r]);
    edge_passA<<<(E + 255) / 256, 256, 0, stream>>>(es[r], ed[r], alS[r], alD[r], seg[r], E);
    float* outp = (r & 1) ? out : out + (size_t)NA * 64;
    edge_passB<<<(E + 3) / 4, 256, 0, stream>>>(es[r], ed[r], alS[r], alD[r], seg[r], P, outp, E);
  }
}

// Round 3
// 1307.352 us; speedup vs baseline: 1.1840x; 1.1840x over previous
//
#include <hip/hip_runtime.h>
#include <hip/hip_bf16.h>

typedef __attribute__((ext_vector_type(8))) short short8;
typedef __attribute__((ext_vector_type(4))) short short4v;
typedef __attribute__((ext_vector_type(4))) float f32x4;

__device__ __forceinline__ unsigned short f2bf(float f) {
  unsigned u = __builtin_bit_cast(unsigned, f);
  u += 0x7FFFu + ((u >> 16) & 1u);
  return (unsigned short)(u >> 16);
}
__device__ __forceinline__ float bf2f(unsigned short b) {
  unsigned u = ((unsigned)b) << 16;
  return __builtin_bit_cast(float, u);
}

// ---------------------------------------------------------------------------
// U tables: U_nodetype[j*128+k], j = r*4+h. Agent is src of r0,r2; dst of r1,r3.
__global__ void prep_u(const float* __restrict__ W, const float* __restrict__ att_src,
                       const float* __restrict__ att_dst,
                       float* __restrict__ U_agent, float* __restrict__ U_track) {
  int idx = blockIdx.x * 256 + threadIdx.x;
  if (idx >= 2 * 16 * 128) return;
  int which = idx >> 11;           // 0 agent, 1 track
  int rem = idx & 2047;
  int j = rem >> 7;                // 0..15
  int k = rem & 127;
  int r = j >> 2, h = j & 3;
  bool srcSide = (which == 0) ? ((r & 1) == 0) : ((r & 1) == 1);
  const float* att = (srcSide ? att_src : att_dst) + (r * 4 + h) * 64;
  const float* Wr = W + (r * 128 + k) * 256 + h * 64;
  float s = 0.f;
#pragma unroll 8
  for (int c = 0; c < 64; ++c) s += Wr[c] * att[c];
  (which ? U_track : U_agent)[j * 128 + k] = s;
}

// Wt[r][c][k] = bf16(W[r][k][c])
__global__ void prep_wt(const float* __restrict__ W, unsigned short* __restrict__ Wt) {
  int idx = blockIdx.x * 256 + threadIdx.x;
  if (idx >= 4 * 256 * 128) return;
  int r = idx >> 15;
  int rem = idx & 32767;
  int c = rem >> 7;
  int k = rem & 127;
  Wt[idx] = f2bf(W[(r * 128 + k) * 256 + c]);
}

// Skinny GEMM [N x 128] @ [128 x 16]: block stages 32 x-rows + U in LDS;
// 8 threads/node compute 2 full dots each. No cross-lane ops.
__global__ __launch_bounds__(256) void node_al2(const float* __restrict__ x,
                                                const float* __restrict__ U, int N,
                                                float* __restrict__ d0, float* __restrict__ d1,
                                                float* __restrict__ d2, float* __restrict__ d3) {
  __shared__ float xs[32 * 132];
  __shared__ float us[16 * 132];
  int tid = threadIdx.x;
  for (int i = tid; i < 2048; i += 256) us[(i >> 7) * 132 + (i & 127)] = U[i];
  int n0 = blockIdx.x * 32;
#pragma unroll
  for (int it = 0; it < 4; ++it) {
    int idx = (it * 256 + tid) * 4;
    int row = idx >> 7, k = idx & 127;
    float4 v = make_float4(0.f, 0.f, 0.f, 0.f);
    if (n0 + row < N) v = *(const float4*)(x + (size_t)(n0 + row) * 128 + k);
    *(float4*)&xs[row * 132 + k] = v;
  }
  __syncthreads();
  int node = tid >> 3;
  int g = n0 + node;
  if (g >= N) return;
  int j0 = (tid & 7) * 2;
  const float* xr = &xs[node * 132];
  const float* u0 = &us[j0 * 132];
  const float* u1 = &us[(j0 + 1) * 132];
  float a0 = 0.f, a1 = 0.f;
#pragma unroll
  for (int k = 0; k < 128; k += 4) {
    float4 xv = *(const float4*)(xr + k);
    float4 v0 = *(const float4*)(u0 + k);
    float4 v1 = *(const float4*)(u1 + k);
    a0 += xv.x * v0.x + xv.y * v0.y + xv.z * v0.z + xv.w * v0.w;
    a1 += xv.x * v1.x + xv.y * v1.y + xv.z * v1.z + xv.w * v1.w;
  }
  int r = j0 >> 2, h = j0 & 3;
  float* dp = (r == 0) ? d0 : (r == 1) ? d1 : (r == 2) ? d2 : d3;
  dp[(size_t)g * 4 + h] = a0;
  dp[(size_t)g * 4 + h + 1] = a1;
}

// out init: 0.5*(bias_a + bias_b) everywhere
__global__ void init_out(float* __restrict__ out, const float* __restrict__ bias,
                         int NA, int NT) {
  int idx = blockIdx.x * 256 + threadIdx.x;
  int total4 = (NA + NT) * 16;
  if (idx >= total4) return;
  int f = idx * 4;
  int c = f & 63;
  const float *b0, *b1;
  if (f < NA * 64) { b0 = bias + 64; b1 = bias + 192; }
  else             { b0 = bias;      b1 = bias + 128; }
  float4 v;
  v.x = 0.5f * (b0[c] + b1[c]);
  v.y = 0.5f * (b0[c + 1] + b1[c + 1]);
  v.z = 0.5f * (b0[c + 2] + b1[c + 2]);
  v.w = 0.5f * (b0[c + 3] + b1[c + 3]);
  *(float4*)(out + f) = v;
}

// P = bf16(X @ W[r]) : [Ns][256], MFMA 16x16x32 bf16
__global__ __launch_bounds__(256) void proj_gemm(const float* __restrict__ X,
                                                 const unsigned short* __restrict__ Wt,
                                                 unsigned short* __restrict__ P, int Ns) {
  __shared__ unsigned short Xs[64 * 136];
  __shared__ unsigned short Ws[128 * 136];
  int tid = threadIdx.x;
  int m0 = blockIdx.x * 64;
  int cs = blockIdx.y * 128;
#pragma unroll
  for (int it = 0; it < 8; ++it) {
    int idx = (tid + it * 256) * 4;
    int row = idx >> 7, k = idx & 127;
    int g = m0 + row;
    float4 v = make_float4(0.f, 0.f, 0.f, 0.f);
    if (g < Ns) v = *(const float4*)(X + (size_t)g * 128 + k);
    short4v sv;
    sv.x = (short)f2bf(v.x); sv.y = (short)f2bf(v.y);
    sv.z = (short)f2bf(v.z); sv.w = (short)f2bf(v.w);
    *(short4v*)&Xs[row * 136 + k] = sv;
  }
#pragma unroll
  for (int it = 0; it < 8; ++it) {
    int idx = (tid + it * 256) * 8;
    int row = idx >> 7, k = idx & 127;
    short8 v = *(const short8*)(Wt + (size_t)(cs + row) * 128 + k);
    *(short8*)&Ws[row * 136 + k] = v;
  }
  __syncthreads();
  int lane = tid & 63, w = tid >> 6;
  f32x4 acc[8];
#pragma unroll
  for (int t = 0; t < 8; ++t) acc[t] = (f32x4){0.f, 0.f, 0.f, 0.f};
  int aoff = (w * 16 + (lane & 15)) * 136 + (lane >> 4) * 8;
  int boff = (lane & 15) * 136 + (lane >> 4) * 8;
#pragma unroll
  for (int kc = 0; kc < 4; ++kc) {
    short8 a = *(const short8*)&Xs[aoff + kc * 32];
#pragma unroll
    for (int t = 0; t < 8; ++t) {
      short8 b = *(const short8*)&Ws[boff + t * 16 * 136 + kc * 32];
      acc[t] = __builtin_amdgcn_mfma_f32_16x16x32_bf16(a, b, acc[t], 0, 0, 0);
    }
  }
#pragma unroll
  for (int t = 0; t < 8; ++t) {
#pragma unroll
    for (int q = 0; q < 4; ++q) {
      int grow = m0 + w * 16 + (lane >> 4) * 4 + q;
      if (grow < Ns) P[(size_t)grow * 256 + cs + t * 16 + (lane & 15)] = f2bf(acc[t][q]);
    }
  }
}

// ---------------------- CSR build (per relation) ----------------------------
__global__ void csr_hist(const int* __restrict__ edst, int* __restrict__ count, int E) {
  int e = blockIdx.x * 256 + threadIdx.x;
  if (e < E) atomicAdd(&count[edst[e]], 1);
}

__global__ void csr_base(const int* __restrict__ count, int* __restrict__ cursor,
                         int* __restrict__ base, int* __restrict__ fill, int Nd) {
  int d = blockIdx.x * 256 + threadIdx.x;
  if (d >= Nd) return;
  int c = count[d];
  int b = atomicAdd(cursor, c);
  base[d] = b;
  fill[d] = b;
}

__global__ void csr_scatter(const int* __restrict__ esrc, const int* __restrict__ edst,
                            int* __restrict__ fill, int* __restrict__ elist, int E) {
  int e = blockIdx.x * 256 + threadIdx.x;
  if (e < E) {
    int pos = atomicAdd(&fill[edst[e]], 1);
    elist[pos] = esrc[e];
  }
}

// One wave per dst: sweep1 = softmax denominators in registers,
// sweep2 = alpha-weighted gather of P rows; single non-atomic RMW to out.
__global__ __launch_bounds__(256) void passB_csr(
    const int* __restrict__ count, const int* __restrict__ base,
    const int* __restrict__ elist,
    const float* __restrict__ alS, const float* __restrict__ alD,
    const unsigned short* __restrict__ P, float* __restrict__ outp, int Nd) {
  int wv = (blockIdx.x * 256 + threadIdx.x) >> 6;
  if (wv >= Nd) return;
  int lane = threadIdx.x & 63;
  int cnt = count[wv];
  int b = base[wv];
  float4 ad = *(const float4*)(alD + (size_t)wv * 4);
  float s0 = 0.f, s1 = 0.f, s2 = 0.f, s3 = 0.f;
  for (int i = 0; i < cnt; ++i) {
    int s = elist[b + i];
    float4 as = *(const float4*)(alS + (size_t)s * 4);
    float v0 = as.x + ad.x, v1 = as.y + ad.y, v2 = as.z + ad.z, v3 = as.w + ad.w;
    v0 = v0 > 0.f ? v0 : 0.2f * v0;
    v1 = v1 > 0.f ? v1 : 0.2f * v1;
    v2 = v2 > 0.f ? v2 : 0.2f * v2;
    v3 = v3 > 0.f ? v3 : 0.2f * v3;
    s0 += __expf(v0); s1 += __expf(v1); s2 += __expf(v2); s3 += __expf(v3);
  }
  float q0 = 0.125f / (s0 + 1e-16f);
  float q1 = 0.125f / (s1 + 1e-16f);
  float q2 = 0.125f / (s2 + 1e-16f);
  float q3 = 0.125f / (s3 + 1e-16f);
  float acc = 0.f;
  for (int i = 0; i < cnt; ++i) {
    int s = elist[b + i];
    float4 as = *(const float4*)(alS + (size_t)s * 4);
    float v0 = as.x + ad.x, v1 = as.y + ad.y, v2 = as.z + ad.z, v3 = as.w + ad.w;
    v0 = v0 > 0.f ? v0 : 0.2f * v0;
    v1 = v1 > 0.f ? v1 : 0.2f * v1;
    v2 = v2 > 0.f ? v2 : 0.2f * v2;
    v3 = v3 > 0.f ? v3 : 0.2f * v3;
    float w0 = __expf(v0) * q0, w1 = __expf(v1) * q1;
    float w2 = __expf(v2) * q2, w3 = __expf(v3) * q3;
    const unsigned short* p = P + (size_t)s * 256;
    acc += w0 * bf2f(p[lane]) + w1 * bf2f(p[64 + lane]) +
           w2 * bf2f(p[128 + lane]) + w3 * bf2f(p[192 + lane]);
  }
  outp[(size_t)wv * 64 + lane] += acc;
}

extern "C" void kernel_launch(void* const* d_in, const int* in_sizes, int n_in,
                              void* d_out, int out_size, void* d_ws, size_t ws_size,
                              hipStream_t stream) {
  const float* x_agent = (const float*)d_in[0];
  const float* x_track = (const float*)d_in[1];
  const float* W = (const float*)d_in[2];
  const float* att_src = (const float*)d_in[3];
  const float* att_dst = (const float*)d_in[4];
  const float* bias = (const float*)d_in[5];
  const int* es[4] = {(const int*)d_in[6], (const int*)d_in[8],
                      (const int*)d_in[10], (const int*)d_in[12]};
  const int* ed[4] = {(const int*)d_in[7], (const int*)d_in[9],
                      (const int*)d_in[11], (const int*)d_in[13]};
  int NA = in_sizes[0] / 128;
  int NT = in_sizes[1] / 128;
  float* out = (float*)d_out;

  int Ns[4] = {NA, NT, NA, NT};
  int Nd[4] = {NT, NA, NT, NA};
  const float* xsrc[4] = {x_agent, x_track, x_agent, x_track};

  char* ws = (char*)d_ws;
  size_t off = 0;
  auto alloc = [&](size_t bytes) -> void* {
    void* p = ws + off;
    off += (bytes + 255) & ~(size_t)255;
    return p;
  };
  int maxN = NA > NT ? NA : NT;
  int maxE = 0;
  for (int r = 0; r < 4; ++r) maxE = in_sizes[6 + 2 * r] > maxE ? in_sizes[6 + 2 * r] : maxE;

  unsigned short* P = (unsigned short*)alloc((size_t)maxN * 256 * 2);
  float *alS[4], *alD[4];
  for (int r = 0; r < 4; ++r) alS[r] = (float*)alloc((size_t)Ns[r] * 4 * 4);
  for (int r = 0; r < 4; ++r) alD[r] = (float*)alloc((size_t)Nd[r] * 4 * 4);
  float* U_agent = (float*)alloc(16 * 128 * 4);
  float* U_track = (float*)alloc(16 * 128 * 4);
  unsigned short* Wt = (unsigned short*)alloc(4 * 256 * 128 * 2);
  int* count = (int*)alloc(((size_t)maxN + 1) * 4);  // +1: cursor at count[maxN]
  int* base = (int*)alloc((size_t)maxN * 4);
  int* fill = (int*)alloc((size_t)maxN * 4);
  int* elist = (int*)alloc((size_t)maxE * 4);

  prep_u<<<16, 256, 0, stream>>>(W, att_src, att_dst, U_agent, U_track);
  prep_wt<<<512, 256, 0, stream>>>(W, Wt);

  node_al2<<<(NA + 31) / 32, 256, 0, stream>>>(x_agent, U_agent, NA,
                                               alS[0], alD[1], alS[2], alD[3]);
  node_al2<<<(NT + 31) / 32, 256, 0, stream>>>(x_track, U_track, NT,
                                               alD[0], alS[1], alD[2], alS[3]);

  int total4 = (NA + NT) * 16;
  init_out<<<(total4 + 255) / 256, 256, 0, stream>>>(out, bias, NA, NT);

  for (int r = 0; r < 4; ++r) {
    int E = in_sizes[6 + 2 * r];
    int nd = Nd[r];
    int* cursor = count + maxN;  // zeroed together with count
    hipMemsetAsync(count, 0, ((size_t)maxN + 1) * 4, stream);
    csr_hist<<<(E + 255) / 256, 256, 0, stream>>>(ed[r], count, E);
    csr_base<<<(nd + 255) / 256, 256, 0, stream>>>(count, cursor, base, fill, nd);
    csr_scatter<<<(E + 255) / 256, 256, 0, stream>>>(es[r], ed[r], fill, elist, E);

    dim3 pg((Ns[r] + 63) / 64, 2);
    proj_gemm<<<pg, 256, 0, stream>>>(xsrc[r], Wt + (size_t)r * 256 * 128, P, Ns[r]);

    float* outp = (r & 1) ? out : out + (size_t)NA * 64;
    passB_csr<<<(nd + 3) / 4, 256, 0, stream>>>(count, base, elist,
                                                alS[r], alD[r], P, outp, nd);
  }
}

// Round 4
// 1178.231 us; speedup vs baseline: 1.3137x; 1.1096x over previous
//
#include <hip/hip_runtime.h>
#include <hip/hip_bf16.h>

typedef __attribute__((ext_vector_type(8))) short short8;
typedef __attribute__((ext_vector_type(4))) short short4v;
typedef __attribute__((ext_vector_type(4))) float f32x4;

__device__ __forceinline__ unsigned short f2bf(float f) {
  unsigned u = __builtin_bit_cast(unsigned, f);
  u += 0x7FFFu + ((u >> 16) & 1u);
  return (unsigned short)(u >> 16);
}
__device__ __forceinline__ float bf2f(unsigned short b) {
  unsigned u = ((unsigned)b) << 16;
  return __builtin_bit_cast(float, u);
}

// ---------------------------------------------------------------------------
// U tables: U_nodetype[j*128+k], j = r*4+h. Agent is src of r0,r2; dst of r1,r3.
__global__ void prep_u(const float* __restrict__ W, const float* __restrict__ att_src,
                       const float* __restrict__ att_dst,
                       float* __restrict__ U_agent, float* __restrict__ U_track) {
  int idx = blockIdx.x * 256 + threadIdx.x;
  if (idx >= 2 * 16 * 128) return;
  int which = idx >> 11;           // 0 agent, 1 track
  int rem = idx & 2047;
  int j = rem >> 7;                // 0..15
  int k = rem & 127;
  int r = j >> 2, h = j & 3;
  bool srcSide = (which == 0) ? ((r & 1) == 0) : ((r & 1) == 1);
  const float* att = (srcSide ? att_src : att_dst) + (r * 4 + h) * 64;
  const float* Wr = W + (r * 128 + k) * 256 + h * 64;
  float s = 0.f;
#pragma unroll 8
  for (int c = 0; c < 64; ++c) s += Wr[c] * att[c];
  (which ? U_track : U_agent)[j * 128 + k] = s;
}

// Wt[r][c][k] = bf16(W[r][k][c])
__global__ void prep_wt(const float* __restrict__ W, unsigned short* __restrict__ Wt) {
  int idx = blockIdx.x * 256 + threadIdx.x;
  if (idx >= 4 * 256 * 128) return;
  int r = idx >> 15;
  int rem = idx & 32767;
  int c = rem >> 7;
  int k = rem & 127;
  Wt[idx] = f2bf(W[(r * 128 + k) * 256 + c]);
}

// Skinny GEMM [N x 128] @ [128 x 16]: block stages 32 x-rows + U in LDS;
// 8 threads/node compute 2 full dots each. No cross-lane ops.
__global__ __launch_bounds__(256) void node_al2(const float* __restrict__ x,
                                                const float* __restrict__ U, int N,
                                                float* __restrict__ d0, float* __restrict__ d1,
                                                float* __restrict__ d2, float* __restrict__ d3) {
  __shared__ float xs[32 * 132];
  __shared__ float us[16 * 132];
  int tid = threadIdx.x;
  for (int i = tid; i < 2048; i += 256) us[(i >> 7) * 132 + (i & 127)] = U[i];
  int n0 = blockIdx.x * 32;
#pragma unroll
  for (int it = 0; it < 4; ++it) {
    int idx = (it * 256 + tid) * 4;
    int row = idx >> 7, k = idx & 127;
    float4 v = make_float4(0.f, 0.f, 0.f, 0.f);
    if (n0 + row < N) v = *(const float4*)(x + (size_t)(n0 + row) * 128 + k);
    *(float4*)&xs[row * 132 + k] = v;
  }
  __syncthreads();
  int node = tid >> 3;
  int g = n0 + node;
  if (g >= N) return;
  int j0 = (tid & 7) * 2;
  const float* xr = &xs[node * 132];
  const float* u0 = &us[j0 * 132];
  const float* u1 = &us[(j0 + 1) * 132];
  float a0 = 0.f, a1 = 0.f;
#pragma unroll
  for (int k = 0; k < 128; k += 4) {
    float4 xv = *(const float4*)(xr + k);
    float4 v0 = *(const float4*)(u0 + k);
    float4 v1 = *(const float4*)(u1 + k);
    a0 += xv.x * v0.x + xv.y * v0.y + xv.z * v0.z + xv.w * v0.w;
    a1 += xv.x * v1.x + xv.y * v1.y + xv.z * v1.z + xv.w * v1.w;
  }
  int r = j0 >> 2, h = j0 & 3;
  float* dp = (r == 0) ? d0 : (r == 1) ? d1 : (r == 2) ? d2 : d3;
  dp[(size_t)g * 4 + h] = a0;
  dp[(size_t)g * 4 + h + 1] = a1;
}

// out init: 0.5*(bias_a + bias_b) everywhere
__global__ void init_out(float* __restrict__ out, const float* __restrict__ bias,
                         int NA, int NT) {
  int idx = blockIdx.x * 256 + threadIdx.x;
  int total4 = (NA + NT) * 16;
  if (idx >= total4) return;
  int f = idx * 4;
  int c = f & 63;
  const float *b0, *b1;
  if (f < NA * 64) { b0 = bias + 64; b1 = bias + 192; }
  else             { b0 = bias;      b1 = bias + 128; }
  float4 v;
  v.x = 0.5f * (b0[c] + b1[c]);
  v.y = 0.5f * (b0[c + 1] + b1[c + 1]);
  v.z = 0.5f * (b0[c + 2] + b1[c + 2]);
  v.w = 0.5f * (b0[c + 3] + b1[c + 3]);
  *(float4*)(out + f) = v;
}

// P = bf16(X @ W[r]) : [Ns][256], MFMA 16x16x32 bf16
__global__ __launch_bounds__(256) void proj_gemm(const float* __restrict__ X,
                                                 const unsigned short* __restrict__ Wt,
                                                 unsigned short* __restrict__ P, int Ns) {
  __shared__ unsigned short Xs[64 * 136];
  __shared__ unsigned short Ws[128 * 136];
  int tid = threadIdx.x;
  int m0 = blockIdx.x * 64;
  int cs = blockIdx.y * 128;
#pragma unroll
  for (int it = 0; it < 8; ++it) {
    int idx = (tid + it * 256) * 4;
    int row = idx >> 7, k = idx & 127;
    int g = m0 + row;
    float4 v = make_float4(0.f, 0.f, 0.f, 0.f);
    if (g < Ns) v = *(const float4*)(X + (size_t)g * 128 + k);
    short4v sv;
    sv.x = (short)f2bf(v.x); sv.y = (short)f2bf(v.y);
    sv.z = (short)f2bf(v.z); sv.w = (short)f2bf(v.w);
    *(short4v*)&Xs[row * 136 + k] = sv;
  }
#pragma unroll
  for (int it = 0; it < 8; ++it) {
    int idx = (tid + it * 256) * 8;
    int row = idx >> 7, k = idx & 127;
    short8 v = *(const short8*)(Wt + (size_t)(cs + row) * 128 + k);
    *(short8*)&Ws[row * 136 + k] = v;
  }
  __syncthreads();
  int lane = tid & 63, w = tid >> 6;
  f32x4 acc[8];
#pragma unroll
  for (int t = 0; t < 8; ++t) acc[t] = (f32x4){0.f, 0.f, 0.f, 0.f};
  int aoff = (w * 16 + (lane & 15)) * 136 + (lane >> 4) * 8;
  int boff = (lane & 15) * 136 + (lane >> 4) * 8;
#pragma unroll
  for (int kc = 0; kc < 4; ++kc) {
    short8 a = *(const short8*)&Xs[aoff + kc * 32];
#pragma unroll
    for (int t = 0; t < 8; ++t) {
      short8 b = *(const short8*)&Ws[boff + t * 16 * 136 + kc * 32];
      acc[t] = __builtin_amdgcn_mfma_f32_16x16x32_bf16(a, b, acc[t], 0, 0, 0);
    }
  }
#pragma unroll
  for (int t = 0; t < 8; ++t) {
#pragma unroll
    for (int q = 0; q < 4; ++q) {
      int grow = m0 + w * 16 + (lane >> 4) * 4 + q;
      if (grow < Ns) P[(size_t)grow * 256 + cs + t * 16 + (lane & 15)] = f2bf(acc[t][q]);
    }
  }
}

// ---------------------- CSR build (per relation) ----------------------------
__global__ void csr_hist(const int* __restrict__ edst, int* __restrict__ count, int E) {
  int e = blockIdx.x * 256 + threadIdx.x;
  if (e < E) atomicAdd(&count[edst[e]], 1);
}

__global__ void csr_base(const int* __restrict__ count, int* __restrict__ cursor,
                         int* __restrict__ base, int* __restrict__ fill, int Nd) {
  int d = blockIdx.x * 256 + threadIdx.x;
  if (d >= Nd) return;
  int c = count[d];
  int b = atomicAdd(cursor, c);
  base[d] = b;
  fill[d] = b;
}

__global__ void csr_scatter(const int* __restrict__ esrc, const int* __restrict__ edst,
                            int* __restrict__ fill, int* __restrict__ elist, int E) {
  int e = blockIdx.x * 256 + threadIdx.x;
  if (e < E) {
    int pos = atomicAdd(&fill[edst[e]], 1);
    elist[pos] = esrc[e];
  }
}

// One wave per dst. Lane layout: h = lane>>4 (head), c4 = (lane&15)*4 (channels).
// Sweep 1: per-lane single-exp denominator (scalar-path loads only).
// Sweep 2: one dwordx2 P load per edge (512 B/wave), fma into 4 channels.
// Cross-head reduce once per dst (8 shuffles), single non-atomic RMW to out.
__global__ __launch_bounds__(256) void passB_csr2(
    const int* __restrict__ count, const int* __restrict__ base,
    const int* __restrict__ elist,
    const float* __restrict__ alS, const float* __restrict__ alD,
    const unsigned short* __restrict__ P, float* __restrict__ outp, int Nd) {
  int wv = (blockIdx.x * 256 + threadIdx.x) >> 6;
  if (wv >= Nd) return;
  int lane = threadIdx.x & 63;
  int h = lane >> 4;
  int cnt = __builtin_amdgcn_readfirstlane(count[wv]);
  int b = __builtin_amdgcn_readfirstlane(base[wv]);
  float4 ad4 = *(const float4*)(alD + (size_t)wv * 4);
  float ad = (h == 0) ? ad4.x : (h == 1) ? ad4.y : (h == 2) ? ad4.z : ad4.w;

  // sweep 1: denominator for this lane's head
  float ssum = 0.f;
  for (int i = 0; i < cnt; ++i) {
    int s = __builtin_amdgcn_readfirstlane(elist[b + i]);
    float4 as4 = *(const float4*)(alS + (size_t)s * 4);
    float v = ((h == 0) ? as4.x : (h == 1) ? as4.y : (h == 2) ? as4.z : as4.w) + ad;
    v = v > 0.f ? v : 0.2f * v;
    ssum += __expf(v);
  }
  float qinv = 0.125f / (ssum + 1e-16f);

  // sweep 2: alpha-weighted gather
  float a0 = 0.f, a1 = 0.f, a2 = 0.f, a3 = 0.f;
  int loff = h * 64 + (lane & 15) * 4;  // ushort offset into P row
#pragma unroll 2
  for (int i = 0; i < cnt; ++i) {
    int s = __builtin_amdgcn_readfirstlane(elist[b + i]);
    float4 as4 = *(const float4*)(alS + (size_t)s * 4);
    float v = ((h == 0) ? as4.x : (h == 1) ? as4.y : (h == 2) ? as4.z : as4.w) + ad;
    v = v > 0.f ? v : 0.2f * v;
    float w = __expf(v) * qinv;
    short4v p4 = *(const short4v*)(P + (size_t)s * 256 + loff);
    a0 += w * bf2f((unsigned short)p4.x);
    a1 += w * bf2f((unsigned short)p4.y);
    a2 += w * bf2f((unsigned short)p4.z);
    a3 += w * bf2f((unsigned short)p4.w);
  }

  // reduce across the 4 head groups (lane bits 4,5); channel id = (lane&15)*4+j
  a0 += __shfl_xor(a0, 16); a0 += __shfl_xor(a0, 32);
  a1 += __shfl_xor(a1, 16); a1 += __shfl_xor(a1, 32);
  a2 += __shfl_xor(a2, 16); a2 += __shfl_xor(a2, 32);
  a3 += __shfl_xor(a3, 16); a3 += __shfl_xor(a3, 32);
  if (lane < 16) {
    float* op = outp + (size_t)wv * 64 + lane * 4;
    float4 cur = *(float4*)op;
    cur.x += a0; cur.y += a1; cur.z += a2; cur.w += a3;
    *(float4*)op = cur;
  }
}

extern "C" void kernel_launch(void* const* d_in, const int* in_sizes, int n_in,
                              void* d_out, int out_size, void* d_ws, size_t ws_size,
                              hipStream_t stream) {
  const float* x_agent = (const float*)d_in[0];
  const float* x_track = (const float*)d_in[1];
  const float* W = (const float*)d_in[2];
  const float* att_src = (const float*)d_in[3];
  const float* att_dst = (const float*)d_in[4];
  const float* bias = (const float*)d_in[5];
  const int* es[4] = {(const int*)d_in[6], (const int*)d_in[8],
                      (const int*)d_in[10], (const int*)d_in[12]};
  const int* ed[4] = {(const int*)d_in[7], (const int*)d_in[9],
                      (const int*)d_in[11], (const int*)d_in[13]};
  int NA = in_sizes[0] / 128;
  int NT = in_sizes[1] / 128;
  float* out = (float*)d_out;

  int Ns[4] = {NA, NT, NA, NT};
  int Nd[4] = {NT, NA, NT, NA};
  const float* xsrc[4] = {x_agent, x_track, x_agent, x_track};

  char* ws = (char*)d_ws;
  size_t off = 0;
  auto alloc = [&](size_t bytes) -> void* {
    void* p = ws + off;
    off += (bytes + 255) & ~(size_t)255;
    return p;
  };
  int maxN = NA > NT ? NA : NT;
  int maxE = 0;
  for (int r = 0; r < 4; ++r) maxE = in_sizes[6 + 2 * r] > maxE ? in_sizes[6 + 2 * r] : maxE;

  unsigned short* P = (unsigned short*)alloc((size_t)maxN * 256 * 2);
  float *alS[4], *alD[4];
  for (int r = 0; r < 4; ++r) alS[r] = (float*)alloc((size_t)Ns[r] * 4 * 4);
  for (int r = 0; r < 4; ++r) alD[r] = (float*)alloc((size_t)Nd[r] * 4 * 4);
  float* U_agent = (float*)alloc(16 * 128 * 4);
  float* U_track = (float*)alloc(16 * 128 * 4);
  unsigned short* Wt = (unsigned short*)alloc(4 * 256 * 128 * 2);
  int* count = (int*)alloc(((size_t)maxN + 1) * 4);  // +1: cursor at count[maxN]
  int* base = (int*)alloc((size_t)maxN * 4);
  int* fill = (int*)alloc((size_t)maxN * 4);
  int* elist = (int*)alloc((size_t)maxE * 4);

  prep_u<<<16, 256, 0, stream>>>(W, att_src, att_dst, U_agent, U_track);
  prep_wt<<<512, 256, 0, stream>>>(W, Wt);

  node_al2<<<(NA + 31) / 32, 256, 0, stream>>>(x_agent, U_agent, NA,
                                               alS[0], alD[1], alS[2], alD[3]);
  node_al2<<<(NT + 31) / 32, 256, 0, stream>>>(x_track, U_track, NT,
                                               alD[0], alS[1], alD[2], alS[3]);

  int total4 = (NA + NT) * 16;
  init_out<<<(total4 + 255) / 256, 256, 0, stream>>>(out, bias, NA, NT);

  for (int r = 0; r < 4; ++r) {
    int E = in_sizes[6 + 2 * r];
    int nd = Nd[r];
    int* cursor = count + maxN;  // zeroed together with count
    hipMemsetAsync(count, 0, ((size_t)maxN + 1) * 4, stream);
    csr_hist<<<(E + 255) / 256, 256, 0, stream>>>(ed[r], count, E);
    csr_base<<<(nd + 255) / 256, 256, 0, stream>>>(count, cursor, base, fill, nd);
    csr_scatter<<<(E + 255) / 256, 256, 0, stream>>>(es[r], ed[r], fill, elist, E);

    dim3 pg((Ns[r] + 63) / 64, 2);
    proj_gemm<<<pg, 256, 0, stream>>>(xsrc[r], Wt + (size_t)r * 256 * 128, P, Ns[r]);

    float* outp = (r & 1) ? out : out + (size_t)NA * 64;
    passB_csr2<<<(nd + 3) / 4, 256, 0, stream>>>(count, base, elist,
                                                 alS[r], alD[r], P, outp, nd);
  }
}

// Round 5
// 1005.858 us; speedup vs baseline: 1.5389x; 1.1714x over previous
//
#include <hip/hip_runtime.h>
#include <hip/hip_bf16.h>

typedef __attribute__((ext_vector_type(8))) short short8;
typedef __attribute__((ext_vector_type(4))) short short4v;
typedef __attribute__((ext_vector_type(4))) float f32x4;

__device__ __forceinline__ unsigned short f2bf(float f) {
  unsigned u = __builtin_bit_cast(unsigned, f);
  u += 0x7FFFu + ((u >> 16) & 1u);
  return (unsigned short)(u >> 16);
}
__device__ __forceinline__ float bf2f(unsigned short b) {
  unsigned u = ((unsigned)b) << 16;
  return __builtin_bit_cast(float, u);
}

// ---------------------------------------------------------------------------
// U tables: U_nodetype[j*128+k], j = r*4+h. Agent is src of r0,r2; dst of r1,r3.
__global__ void prep_u(const float* __restrict__ W, const float* __restrict__ att_src,
                       const float* __restrict__ att_dst,
                       float* __restrict__ U_agent, float* __restrict__ U_track) {
  int idx = blockIdx.x * 256 + threadIdx.x;
  if (idx >= 2 * 16 * 128) return;
  int which = idx >> 11;           // 0 agent, 1 track
  int rem = idx & 2047;
  int j = rem >> 7;                // 0..15
  int k = rem & 127;
  int r = j >> 2, h = j & 3;
  bool srcSide = (which == 0) ? ((r & 1) == 0) : ((r & 1) == 1);
  const float* att = (srcSide ? att_src : att_dst) + (r * 4 + h) * 64;
  const float* Wr = W + (r * 128 + k) * 256 + h * 64;
  float s = 0.f;
#pragma unroll 8
  for (int c = 0; c < 64; ++c) s += Wr[c] * att[c];
  (which ? U_track : U_agent)[j * 128 + k] = s;
}

// Wt[r][c][k] = bf16(W[r][k][c])
__global__ void prep_wt(const float* __restrict__ W, unsigned short* __restrict__ Wt) {
  int idx = blockIdx.x * 256 + threadIdx.x;
  if (idx >= 4 * 256 * 128) return;
  int r = idx >> 15;
  int rem = idx & 32767;
  int c = rem >> 7;
  int k = rem & 127;
  Wt[idx] = f2bf(W[(r * 128 + k) * 256 + c]);
}

// Skinny GEMM [N x 128] @ [128 x 16]: block stages 32 x-rows + U in LDS;
// 8 threads/node compute 2 full dots each. No cross-lane ops.
__global__ __launch_bounds__(256) void node_al2(const float* __restrict__ x,
                                                const float* __restrict__ U, int N,
                                                float* __restrict__ d0, float* __restrict__ d1,
                                                float* __restrict__ d2, float* __restrict__ d3) {
  __shared__ float xs[32 * 132];
  __shared__ float us[16 * 132];
  int tid = threadIdx.x;
  for (int i = tid; i < 2048; i += 256) us[(i >> 7) * 132 + (i & 127)] = U[i];
  int n0 = blockIdx.x * 32;
#pragma unroll
  for (int it = 0; it < 4; ++it) {
    int idx = (it * 256 + tid) * 4;
    int row = idx >> 7, k = idx & 127;
    float4 v = make_float4(0.f, 0.f, 0.f, 0.f);
    if (n0 + row < N) v = *(const float4*)(x + (size_t)(n0 + row) * 128 + k);
    *(float4*)&xs[row * 132 + k] = v;
  }
  __syncthreads();
  int node = tid >> 3;
  int g = n0 + node;
  if (g >= N) return;
  int j0 = (tid & 7) * 2;
  const float* xr = &xs[node * 132];
  const float* u0 = &us[j0 * 132];
  const float* u1 = &us[(j0 + 1) * 132];
  float a0 = 0.f, a1 = 0.f;
#pragma unroll
  for (int k = 0; k < 128; k += 4) {
    float4 xv = *(const float4*)(xr + k);
    float4 v0 = *(const float4*)(u0 + k);
    float4 v1 = *(const float4*)(u1 + k);
    a0 += xv.x * v0.x + xv.y * v0.y + xv.z * v0.z + xv.w * v0.w;
    a1 += xv.x * v1.x + xv.y * v1.y + xv.z * v1.z + xv.w * v1.w;
  }
  int r = j0 >> 2, h = j0 & 3;
  float* dp = (r == 0) ? d0 : (r == 1) ? d1 : (r == 2) ? d2 : d3;
  dp[(size_t)g * 4 + h] = a0;
  dp[(size_t)g * 4 + h + 1] = a1;
}

// out init: 0.5*(bias_a + bias_b) everywhere
__global__ void init_out(float* __restrict__ out, const float* __restrict__ bias,
                         int NA, int NT) {
  int idx = blockIdx.x * 256 + threadIdx.x;
  int total4 = (NA + NT) * 16;
  if (idx >= total4) return;
  int f = idx * 4;
  int c = f & 63;
  const float *b0, *b1;
  if (f < NA * 64) { b0 = bias + 64; b1 = bias + 192; }
  else             { b0 = bias;      b1 = bias + 128; }
  float4 v;
  v.x = 0.5f * (b0[c] + b1[c]);
  v.y = 0.5f * (b0[c + 1] + b1[c + 1]);
  v.z = 0.5f * (b0[c + 2] + b1[c + 2]);
  v.w = 0.5f * (b0[c + 3] + b1[c + 3]);
  *(float4*)(out + f) = v;
}

// P = bf16(X @ W[r]) : [Ns][256], MFMA 16x16x32 bf16
__global__ __launch_bounds__(256) void proj_gemm(const float* __restrict__ X,
                                                 const unsigned short* __restrict__ Wt,
                                                 unsigned short* __restrict__ P, int Ns) {
  __shared__ unsigned short Xs[64 * 136];
  __shared__ unsigned short Ws[128 * 136];
  int tid = threadIdx.x;
  int m0 = blockIdx.x * 64;
  int cs = blockIdx.y * 128;
#pragma unroll
  for (int it = 0; it < 8; ++it) {
    int idx = (tid + it * 256) * 4;
    int row = idx >> 7, k = idx & 127;
    int g = m0 + row;
    float4 v = make_float4(0.f, 0.f, 0.f, 0.f);
    if (g < Ns) v = *(const float4*)(X + (size_t)g * 128 + k);
    short4v sv;
    sv.x = (short)f2bf(v.x); sv.y = (short)f2bf(v.y);
    sv.z = (short)f2bf(v.z); sv.w = (short)f2bf(v.w);
    *(short4v*)&Xs[row * 136 + k] = sv;
  }
#pragma unroll
  for (int it = 0; it < 8; ++it) {
    int idx = (tid + it * 256) * 8;
    int row = idx >> 7, k = idx & 127;
    short8 v = *(const short8*)(Wt + (size_t)(cs + row) * 128 + k);
    *(short8*)&Ws[row * 136 + k] = v;
  }
  __syncthreads();
  int lane = tid & 63, w = tid >> 6;
  f32x4 acc[8];
#pragma unroll
  for (int t = 0; t < 8; ++t) acc[t] = (f32x4){0.f, 0.f, 0.f, 0.f};
  int aoff = (w * 16 + (lane & 15)) * 136 + (lane >> 4) * 8;
  int boff = (lane & 15) * 136 + (lane >> 4) * 8;
#pragma unroll
  for (int kc = 0; kc < 4; ++kc) {
    short8 a = *(const short8*)&Xs[aoff + kc * 32];
#pragma unroll
    for (int t = 0; t < 8; ++t) {
      short8 b = *(const short8*)&Ws[boff + t * 16 * 136 + kc * 32];
      acc[t] = __builtin_amdgcn_mfma_f32_16x16x32_bf16(a, b, acc[t], 0, 0, 0);
    }
  }
#pragma unroll
  for (int t = 0; t < 8; ++t) {
#pragma unroll
    for (int q = 0; q < 4; ++q) {
      int grow = m0 + w * 16 + (lane >> 4) * 4 + q;
      if (grow < Ns) P[(size_t)grow * 256 + cs + t * 16 + (lane & 15)] = f2bf(acc[t][q]);
    }
  }
}

// ---------------------- CSR build (per relation) ----------------------------
__global__ void csr_hist(const int* __restrict__ edst, int* __restrict__ count, int E) {
  int e = blockIdx.x * 256 + threadIdx.x;
  if (e < E) atomicAdd(&count[edst[e]], 1);
}

__global__ void csr_base(const int* __restrict__ count, int* __restrict__ cursor,
                         int* __restrict__ base, int* __restrict__ fill, int Nd) {
  int d = blockIdx.x * 256 + threadIdx.x;
  if (d >= Nd) return;
  int c = count[d];
  int b = atomicAdd(cursor, c);
  base[d] = b;
  fill[d] = b;
}

__global__ void csr_scatter(const int* __restrict__ esrc, const int* __restrict__ edst,
                            int* __restrict__ fill, int* __restrict__ elist, int E) {
  int e = blockIdx.x * 256 + threadIdx.x;
  if (e < E) {
    int pos = atomicAdd(&fill[edst[e]], 1);
    elist[pos] = esrc[e];
  }
}

// Fused single-sweep softmax+gather. One wave per dst.
// Lane layout: h = lane>>4, channels (lane&15)*4 .. +3.
// Accumulate unnormalized numerator + denominator, normalize at end.
// 4-edge manual pipeline -> 4 independent load chains in flight.
__global__ __launch_bounds__(256) void passB_fused(
    const int* __restrict__ count, const int* __restrict__ base,
    const int* __restrict__ elist,
    const float* __restrict__ alS, const float* __restrict__ alD,
    const unsigned short* __restrict__ P, float* __restrict__ outp, int Nd) {
  int wv = (blockIdx.x * 256 + threadIdx.x) >> 6;
  if (wv >= Nd) return;
  int lane = threadIdx.x & 63;
  int h = lane >> 4;
  int cnt = __builtin_amdgcn_readfirstlane(count[wv]);
  if (cnt == 0) return;
  int b = __builtin_amdgcn_readfirstlane(base[wv]);
  float4 ad4 = *(const float4*)(alD + (size_t)wv * 4);
  float ad = (h == 0) ? ad4.x : (h == 1) ? ad4.y : (h == 2) ? ad4.z : ad4.w;

  float den = 0.f;
  float n0 = 0.f, n1 = 0.f, n2 = 0.f, n3 = 0.f;
  int loff = h * 64 + (lane & 15) * 4;  // ushort offset into P row

  int i = 0;
  for (; i + 4 <= cnt; i += 4) {
    int s0 = __builtin_amdgcn_readfirstlane(elist[b + i]);
    int s1 = __builtin_amdgcn_readfirstlane(elist[b + i + 1]);
    int s2 = __builtin_amdgcn_readfirstlane(elist[b + i + 2]);
    int s3 = __builtin_amdgcn_readfirstlane(elist[b + i + 3]);
    float4 A0 = *(const float4*)(alS + (size_t)s0 * 4);
    float4 A1 = *(const float4*)(alS + (size_t)s1 * 4);
    float4 A2 = *(const float4*)(alS + (size_t)s2 * 4);
    float4 A3 = *(const float4*)(alS + (size_t)s3 * 4);
    short4v p0 = *(const short4v*)(P + (size_t)s0 * 256 + loff);
    short4v p1 = *(const short4v*)(P + (size_t)s1 * 256 + loff);
    short4v p2 = *(const short4v*)(P + (size_t)s2 * 256 + loff);
    short4v p3 = *(const short4v*)(P + (size_t)s3 * 256 + loff);
    float v0 = ((h == 0) ? A0.x : (h == 1) ? A0.y : (h == 2) ? A0.z : A0.w) + ad;
    float v1 = ((h == 0) ? A1.x : (h == 1) ? A1.y : (h == 2) ? A1.z : A1.w) + ad;
    float v2 = ((h == 0) ? A2.x : (h == 1) ? A2.y : (h == 2) ? A2.z : A2.w) + ad;
    float v3 = ((h == 0) ? A3.x : (h == 1) ? A3.y : (h == 2) ? A3.z : A3.w) + ad;
    v0 = v0 > 0.f ? v0 : 0.2f * v0;
    v1 = v1 > 0.f ? v1 : 0.2f * v1;
    v2 = v2 > 0.f ? v2 : 0.2f * v2;
    v3 = v3 > 0.f ? v3 : 0.2f * v3;
    float e0 = __expf(v0), e1 = __expf(v1), e2 = __expf(v2), e3 = __expf(v3);
    den += (e0 + e1) + (e2 + e3);
    n0 += e0 * bf2f((unsigned short)p0.x) + e1 * bf2f((unsigned short)p1.x) +
          e2 * bf2f((unsigned short)p2.x) + e3 * bf2f((unsigned short)p3.x);
    n1 += e0 * bf2f((unsigned short)p0.y) + e1 * bf2f((unsigned short)p1.y) +
          e2 * bf2f((unsigned short)p2.y) + e3 * bf2f((unsigned short)p3.y);
    n2 += e0 * bf2f((unsigned short)p0.z) + e1 * bf2f((unsigned short)p1.z) +
          e2 * bf2f((unsigned short)p2.z) + e3 * bf2f((unsigned short)p3.z);
    n3 += e0 * bf2f((unsigned short)p0.w) + e1 * bf2f((unsigned short)p1.w) +
          e2 * bf2f((unsigned short)p2.w) + e3 * bf2f((unsigned short)p3.w);
  }
  for (; i < cnt; ++i) {
    int s = __builtin_amdgcn_readfirstlane(elist[b + i]);
    float4 A = *(const float4*)(alS + (size_t)s * 4);
    short4v p = *(const short4v*)(P + (size_t)s * 256 + loff);
    float v = ((h == 0) ? A.x : (h == 1) ? A.y : (h == 2) ? A.z : A.w) + ad;
    v = v > 0.f ? v : 0.2f * v;
    float e = __expf(v);
    den += e;
    n0 += e * bf2f((unsigned short)p.x);
    n1 += e * bf2f((unsigned short)p.y);
    n2 += e * bf2f((unsigned short)p.z);
    n3 += e * bf2f((unsigned short)p.w);
  }

  float q = 0.125f / (den + 1e-16f);
  n0 *= q; n1 *= q; n2 *= q; n3 *= q;

  n0 += __shfl_xor(n0, 16); n0 += __shfl_xor(n0, 32);
  n1 += __shfl_xor(n1, 16); n1 += __shfl_xor(n1, 32);
  n2 += __shfl_xor(n2, 16); n2 += __shfl_xor(n2, 32);
  n3 += __shfl_xor(n3, 16); n3 += __shfl_xor(n3, 32);
  if (lane < 16) {
    float* op = outp + (size_t)wv * 64 + lane * 4;
    float4 cur = *(float4*)op;
    cur.x += n0; cur.y += n1; cur.z += n2; cur.w += n3;
    *(float4*)op = cur;
  }
}

extern "C" void kernel_launch(void* const* d_in, const int* in_sizes, int n_in,
                              void* d_out, int out_size, void* d_ws, size_t ws_size,
                              hipStream_t stream) {
  const float* x_agent = (const float*)d_in[0];
  const float* x_track = (const float*)d_in[1];
  const float* W = (const float*)d_in[2];
  const float* att_src = (const float*)d_in[3];
  const float* att_dst = (const float*)d_in[4];
  const float* bias = (const float*)d_in[5];
  const int* es[4] = {(const int*)d_in[6], (const int*)d_in[8],
                      (const int*)d_in[10], (const int*)d_in[12]};
  const int* ed[4] = {(const int*)d_in[7], (const int*)d_in[9],
                      (const int*)d_in[11], (const int*)d_in[13]};
  int NA = in_sizes[0] / 128;
  int NT = in_sizes[1] / 128;
  float* out = (float*)d_out;

  int Ns[4] = {NA, NT, NA, NT};
  int Nd[4] = {NT, NA, NT, NA};
  const float* xsrc[4] = {x_agent, x_track, x_agent, x_track};

  char* ws = (char*)d_ws;
  size_t off = 0;
  auto alloc = [&](size_t bytes) -> void* {
    void* p = ws + off;
    off += (bytes + 255) & ~(size_t)255;
    return p;
  };
  int maxN = NA > NT ? NA : NT;
  int maxE = 0;
  for (int r = 0; r < 4; ++r) maxE = in_sizes[6 + 2 * r] > maxE ? in_sizes[6 + 2 * r] : maxE;

  unsigned short* P = (unsigned short*)alloc((size_t)maxN * 256 * 2);
  float *alS[4], *alD[4];
  for (int r = 0; r < 4; ++r) alS[r] = (float*)alloc((size_t)Ns[r] * 4 * 4);
  for (int r = 0; r < 4; ++r) alD[r] = (float*)alloc((size_t)Nd[r] * 4 * 4);
  float* U_agent = (float*)alloc(16 * 128 * 4);
  float* U_track = (float*)alloc(16 * 128 * 4);
  unsigned short* Wt = (unsigned short*)alloc(4 * 256 * 128 * 2);
  int* count = (int*)alloc(((size_t)maxN + 1) * 4);  // +1: cursor at count[maxN]
  int* base = (int*)alloc((size_t)maxN * 4);
  int* fill = (int*)alloc((size_t)maxN * 4);
  int* elist = (int*)alloc((size_t)maxE * 4);

  prep_u<<<16, 256, 0, stream>>>(W, att_src, att_dst, U_agent, U_track);
  prep_wt<<<512, 256, 0, stream>>>(W, Wt);

  node_al2<<<(NA + 31) / 32, 256, 0, stream>>>(x_agent, U_agent, NA,
                                               alS[0], alD[1], alS[2], alD[3]);
  node_al2<<<(NT + 31) / 32, 256, 0, stream>>>(x_track, U_track, NT,
                                               alD[0], alS[1], alD[2], alS[3]);

  int total4 = (NA + NT) * 16;
  init_out<<<(total4 + 255) / 256, 256, 0, stream>>>(out, bias, NA, NT);

  for (int r = 0; r < 4; ++r) {
    int E = in_sizes[6 + 2 * r];
    int nd = Nd[r];
    int* cursor = count + maxN;  // zeroed together with count
    hipMemsetAsync(count, 0, ((size_t)maxN + 1) * 4, stream);
    csr_hist<<<(E + 255) / 256, 256, 0, stream>>>(ed[r], count, E);
    csr_base<<<(nd + 255) / 256, 256, 0, stream>>>(count, cursor, base, fill, nd);
    csr_scatter<<<(E + 255) / 256, 256, 0, stream>>>(es[r], ed[r], fill, elist, E);

    dim3 pg((Ns[r] + 63) / 64, 2);
    proj_gemm<<<pg, 256, 0, stream>>>(xsrc[r], Wt + (size_t)r * 256 * 128, P, Ns[r]);

    float* outp = (r & 1) ? out : out + (size_t)NA * 64;
    passB_fused<<<(nd + 3) / 4, 256, 0, stream>>>(count, base, elist,
                                                  alS[r], alD[r], P, outp, nd);
  }
}

// Round 6
// 971.474 us; speedup vs baseline: 1.5934x; 1.0354x over previous
//
#include <hip/hip_runtime.h>
#include <hip/hip_bf16.h>

typedef __attribute__((ext_vector_type(8))) short short8;
typedef __attribute__((ext_vector_type(4))) short short4v;
typedef __attribute__((ext_vector_type(4))) float f32x4;

__device__ __forceinline__ unsigned short f2bf(float f) {
  unsigned u = __builtin_bit_cast(unsigned, f);
  u += 0x7FFFu + ((u >> 16) & 1u);
  return (unsigned short)(u >> 16);
}
__device__ __forceinline__ float bf2f(unsigned short b) {
  unsigned u = ((unsigned)b) << 16;
  return __builtin_bit_cast(float, u);
}

// ---------------------------------------------------------------------------
// U tables: U_nodetype[j*128+k], j = r*4+h. Agent is src of r0,r2; dst of r1,r3.
__global__ void prep_u(const float* __restrict__ W, const float* __restrict__ att_src,
                       const float* __restrict__ att_dst,
                       float* __restrict__ U_agent, float* __restrict__ U_track) {
  int idx = blockIdx.x * 256 + threadIdx.x;
  if (idx >= 2 * 16 * 128) return;
  int which = idx >> 11;           // 0 agent, 1 track
  int rem = idx & 2047;
  int j = rem >> 7;                // 0..15
  int k = rem & 127;
  int r = j >> 2, h = j & 3;
  bool srcSide = (which == 0) ? ((r & 1) == 0) : ((r & 1) == 1);
  const float* att = (srcSide ? att_src : att_dst) + (r * 4 + h) * 64;
  const float* Wr = W + (r * 128 + k) * 256 + h * 64;
  float s = 0.f;
#pragma unroll 8
  for (int c = 0; c < 64; ++c) s += Wr[c] * att[c];
  (which ? U_track : U_agent)[j * 128 + k] = s;
}

// Wt[r][c][k] = bf16(W[r][k][c])
__global__ void prep_wt(const float* __restrict__ W, unsigned short* __restrict__ Wt) {
  int idx = blockIdx.x * 256 + threadIdx.x;
  if (idx >= 4 * 256 * 128) return;
  int r = idx >> 15;
  int rem = idx & 32767;
  int c = rem >> 7;
  int k = rem & 127;
  Wt[idx] = f2bf(W[(r * 128 + k) * 256 + c]);
}

// Skinny GEMM [N x 128] @ [128 x 16]: block stages 32 x-rows + U in LDS;
// 8 threads/node compute 2 full dots each. No cross-lane ops.
__global__ __launch_bounds__(256) void node_al2(const float* __restrict__ x,
                                                const float* __restrict__ U, int N,
                                                float* __restrict__ d0, float* __restrict__ d1,
                                                float* __restrict__ d2, float* __restrict__ d3) {
  __shared__ float xs[32 * 132];
  __shared__ float us[16 * 132];
  int tid = threadIdx.x;
  for (int i = tid; i < 2048; i += 256) us[(i >> 7) * 132 + (i & 127)] = U[i];
  int n0 = blockIdx.x * 32;
#pragma unroll
  for (int it = 0; it < 4; ++it) {
    int idx = (it * 256 + tid) * 4;
    int row = idx >> 7, k = idx & 127;
    float4 v = make_float4(0.f, 0.f, 0.f, 0.f);
    if (n0 + row < N) v = *(const float4*)(x + (size_t)(n0 + row) * 128 + k);
    *(float4*)&xs[row * 132 + k] = v;
  }
  __syncthreads();
  int node = tid >> 3;
  int g = n0 + node;
  if (g >= N) return;
  int j0 = (tid & 7) * 2;
  const float* xr = &xs[node * 132];
  const float* u0 = &us[j0 * 132];
  const float* u1 = &us[(j0 + 1) * 132];
  float a0 = 0.f, a1 = 0.f;
#pragma unroll
  for (int k = 0; k < 128; k += 4) {
    float4 xv = *(const float4*)(xr + k);
    float4 v0 = *(const float4*)(u0 + k);
    float4 v1 = *(const float4*)(u1 + k);
    a0 += xv.x * v0.x + xv.y * v0.y + xv.z * v0.z + xv.w * v0.w;
    a1 += xv.x * v1.x + xv.y * v1.y + xv.z * v1.z + xv.w * v1.w;
  }
  int r = j0 >> 2, h = j0 & 3;
  float* dp = (r == 0) ? d0 : (r == 1) ? d1 : (r == 2) ? d2 : d3;
  dp[(size_t)g * 4 + h] = a0;
  dp[(size_t)g * 4 + h + 1] = a1;
}

// out init: 0.5*(bias_a + bias_b) everywhere
__global__ void init_out(float* __restrict__ out, const float* __restrict__ bias,
                         int NA, int NT) {
  int idx = blockIdx.x * 256 + threadIdx.x;
  int total4 = (NA + NT) * 16;
  if (idx >= total4) return;
  int f = idx * 4;
  int c = f & 63;
  const float *b0, *b1;
  if (f < NA * 64) { b0 = bias + 64; b1 = bias + 192; }
  else             { b0 = bias;      b1 = bias + 128; }
  float4 v;
  v.x = 0.5f * (b0[c] + b1[c]);
  v.y = 0.5f * (b0[c + 1] + b1[c + 1]);
  v.z = 0.5f * (b0[c + 2] + b1[c + 2]);
  v.w = 0.5f * (b0[c + 3] + b1[c + 3]);
  *(float4*)(out + f) = v;
}

// P = bf16(X @ W[r]) : [Ns][256], MFMA 16x16x32 bf16
__global__ __launch_bounds__(256) void proj_gemm(const float* __restrict__ X,
                                                 const unsigned short* __restrict__ Wt,
                                                 unsigned short* __restrict__ P, int Ns) {
  __shared__ unsigned short Xs[64 * 136];
  __shared__ unsigned short Ws[128 * 136];
  int tid = threadIdx.x;
  int m0 = blockIdx.x * 64;
  int cs = blockIdx.y * 128;
#pragma unroll
  for (int it = 0; it < 8; ++it) {
    int idx = (tid + it * 256) * 4;
    int row = idx >> 7, k = idx & 127;
    int g = m0 + row;
    float4 v = make_float4(0.f, 0.f, 0.f, 0.f);
    if (g < Ns) v = *(const float4*)(X + (size_t)g * 128 + k);
    short4v sv;
    sv.x = (short)f2bf(v.x); sv.y = (short)f2bf(v.y);
    sv.z = (short)f2bf(v.z); sv.w = (short)f2bf(v.w);
    *(short4v*)&Xs[row * 136 + k] = sv;
  }
#pragma unroll
  for (int it = 0; it < 8; ++it) {
    int idx = (tid + it * 256) * 8;
    int row = idx >> 7, k = idx & 127;
    short8 v = *(const short8*)(Wt + (size_t)(cs + row) * 128 + k);
    *(short8*)&Ws[row * 136 + k] = v;
  }
  __syncthreads();
  int lane = tid & 63, w = tid >> 6;
  f32x4 acc[8];
#pragma unroll
  for (int t = 0; t < 8; ++t) acc[t] = (f32x4){0.f, 0.f, 0.f, 0.f};
  int aoff = (w * 16 + (lane & 15)) * 136 + (lane >> 4) * 8;
  int boff = (lane & 15) * 136 + (lane >> 4) * 8;
#pragma unroll
  for (int kc = 0; kc < 4; ++kc) {
    short8 a = *(const short8*)&Xs[aoff + kc * 32];
#pragma unroll
    for (int t = 0; t < 8; ++t) {
      short8 b = *(const short8*)&Ws[boff + t * 16 * 136 + kc * 32];
      acc[t] = __builtin_amdgcn_mfma_f32_16x16x32_bf16(a, b, acc[t], 0, 0, 0);
    }
  }
#pragma unroll
  for (int t = 0; t < 8; ++t) {
#pragma unroll
    for (int q = 0; q < 4; ++q) {
      int grow = m0 + w * 16 + (lane >> 4) * 4 + q;
      if (grow < Ns) P[(size_t)grow * 256 + cs + t * 16 + (lane & 15)] = f2bf(acc[t][q]);
    }
  }
}

// ---------------------- CSR build (per relation) ----------------------------
__global__ void csr_hist(const int* __restrict__ edst, int* __restrict__ count, int E) {
  int e = blockIdx.x * 256 + threadIdx.x;
  if (e < E) atomicAdd(&count[edst[e]], 1);
}

__global__ void csr_base(const int* __restrict__ count, int* __restrict__ cursor,
                         int* __restrict__ base, int* __restrict__ fill, int Nd) {
  int d = blockIdx.x * 256 + threadIdx.x;
  if (d >= Nd) return;
  int c = count[d];
  int b = atomicAdd(cursor, c);
  base[d] = b;
  fill[d] = b;
}

__global__ void csr_scatter(const int* __restrict__ esrc, const int* __restrict__ edst,
                            int* __restrict__ fill, int* __restrict__ elist, int E) {
  int e = blockIdx.x * 256 + threadIdx.x;
  if (e < E) {
    int pos = atomicAdd(&fill[edst[e]], 1);
    elist[pos] = esrc[e];
  }
}

// Fused softmax+gather, 32 lanes per dst (2 dsts per wave).
// Lane j in group: head h = j>>3, channel block cb = (j&7)*8 (8 channels, 16B).
// Per edge each lane loads one dwordx4 of P -> 1 KB per wave VMEM instruction.
// Unroll 2: two independent load chains per group. Single RMW to out.
__global__ __launch_bounds__(256) void passB_v3(
    const int* __restrict__ count, const int* __restrict__ base,
    const int* __restrict__ elist,
    const float* __restrict__ alS, const float* __restrict__ alD,
    const unsigned short* __restrict__ P, float* __restrict__ outp, int Nd) {
  int grp = (blockIdx.x * 256 + threadIdx.x) >> 5;
  if (grp >= Nd) return;
  int l = threadIdx.x & 31;
  int h = l >> 3;
  int cb = (l & 7) * 8;
  int cnt = count[grp];
  int b = base[grp];
  float ad = alD[(size_t)grp * 4 + h];
  int loff = h * 64 + cb;  // ushort offset into P row

  float den = 0.f;
  float acc[8];
#pragma unroll
  for (int j = 0; j < 8; ++j) acc[j] = 0.f;

  for (int i = 0; i < cnt; i += 2) {
    bool two = (i + 1 < cnt);
    int s0 = elist[b + i];
    int s1 = two ? elist[b + i + 1] : s0;
    float v0 = alS[(size_t)s0 * 4 + h] + ad;
    float v1 = alS[(size_t)s1 * 4 + h] + ad;
    short8 p0 = *(const short8*)(P + (size_t)s0 * 256 + loff);
    short8 p1 = *(const short8*)(P + (size_t)s1 * 256 + loff);
    v0 = v0 > 0.f ? v0 : 0.2f * v0;
    v1 = v1 > 0.f ? v1 : 0.2f * v1;
    float e0 = __expf(v0);
    float e1 = two ? __expf(v1) : 0.f;
    den += e0 + e1;
#pragma unroll
    for (int j = 0; j < 8; ++j)
      acc[j] += e0 * bf2f((unsigned short)p0[j]) + e1 * bf2f((unsigned short)p1[j]);
  }

  float q = 0.125f / (den + 1e-16f);
#pragma unroll
  for (int j = 0; j < 8; ++j) {
    float a = acc[j] * q;
    a += __shfl_xor(a, 8);
    a += __shfl_xor(a, 16);
    acc[j] = a;
  }
  // lanes 0..7 of each group write 8 consecutive floats (channel block = lane&7)
  if (l < 8) {
    float* op = outp + (size_t)grp * 64 + l * 8;
    float4 c0 = *(float4*)op;
    float4 c1 = *(float4*)(op + 4);
    c0.x += acc[0]; c0.y += acc[1]; c0.z += acc[2]; c0.w += acc[3];
    c1.x += acc[4]; c1.y += acc[5]; c1.z += acc[6]; c1.w += acc[7];
    *(float4*)op = c0;
    *(float4*)(op + 4) = c1;
  }
}

extern "C" void kernel_launch(void* const* d_in, const int* in_sizes, int n_in,
                              void* d_out, int out_size, void* d_ws, size_t ws_size,
                              hipStream_t stream) {
  const float* x_agent = (const float*)d_in[0];
  const float* x_track = (const float*)d_in[1];
  const float* W = (const float*)d_in[2];
  const float* att_src = (const float*)d_in[3];
  const float* att_dst = (const float*)d_in[4];
  const float* bias = (const float*)d_in[5];
  const int* es[4] = {(const int*)d_in[6], (const int*)d_in[8],
                      (const int*)d_in[10], (const int*)d_in[12]};
  const int* ed[4] = {(const int*)d_in[7], (const int*)d_in[9],
                      (const int*)d_in[11], (const int*)d_in[13]};
  int NA = in_sizes[0] / 128;
  int NT = in_sizes[1] / 128;
  float* out = (float*)d_out;

  int Ns[4] = {NA, NT, NA, NT};
  int Nd[4] = {NT, NA, NT, NA};
  const float* xsrc[4] = {x_agent, x_track, x_agent, x_track};

  char* ws = (char*)d_ws;
  size_t off = 0;
  auto alloc = [&](size_t bytes) -> void* {
    void* p = ws + off;
    off += (bytes + 255) & ~(size_t)255;
    return p;
  };
  int maxN = NA > NT ? NA : NT;
  int maxE = 0;
  for (int r = 0; r < 4; ++r) maxE = in_sizes[6 + 2 * r] > maxE ? in_sizes[6 + 2 * r] : maxE;

  unsigned short* P = (unsigned short*)alloc((size_t)maxN * 256 * 2);
  float *alS[4], *alD[4];
  for (int r = 0; r < 4; ++r) alS[r] = (float*)alloc((size_t)Ns[r] * 4 * 4);
  for (int r = 0; r < 4; ++r) alD[r] = (float*)alloc((size_t)Nd[r] * 4 * 4);
  float* U_agent = (float*)alloc(16 * 128 * 4);
  float* U_track = (float*)alloc(16 * 128 * 4);
  unsigned short* Wt = (unsigned short*)alloc(4 * 256 * 128 * 2);
  int* count = (int*)alloc(((size_t)maxN + 1) * 4);  // +1: cursor at count[maxN]
  int* base = (int*)alloc((size_t)maxN * 4);
  int* fill = (int*)alloc((size_t)maxN * 4);
  int* elist = (int*)alloc((size_t)maxE * 4);

  prep_u<<<16, 256, 0, stream>>>(W, att_src, att_dst, U_agent, U_track);
  prep_wt<<<512, 256, 0, stream>>>(W, Wt);

  node_al2<<<(NA + 31) / 32, 256, 0, stream>>>(x_agent, U_agent, NA,
                                               alS[0], alD[1], alS[2], alD[3]);
  node_al2<<<(NT + 31) / 32, 256, 0, stream>>>(x_track, U_track, NT,
                                               alD[0], alS[1], alD[2], alS[3]);

  int total4 = (NA + NT) * 16;
  init_out<<<(total4 + 255) / 256, 256, 0, stream>>>(out, bias, NA, NT);

  for (int r = 0; r < 4; ++r) {
    int E = in_sizes[6 + 2 * r];
    int nd = Nd[r];
    int* cursor = count + maxN;  // zeroed together with count
    hipMemsetAsync(count, 0, ((size_t)maxN + 1) * 4, stream);
    csr_hist<<<(E + 255) / 256, 256, 0, stream>>>(ed[r], count, E);
    csr_base<<<(nd + 255) / 256, 256, 0, stream>>>(count, cursor, base, fill, nd);
    csr_scatter<<<(E + 255) / 256, 256, 0, stream>>>(es[r], ed[r], fill, elist, E);

    dim3 pg((Ns[r] + 63) / 64, 2);
    proj_gemm<<<pg, 256, 0, stream>>>(xsrc[r], Wt + (size_t)r * 256 * 128, P, Ns[r]);

    float* outp = (r & 1) ? out : out + (size_t)NA * 64;
    passB_v3<<<(nd + 7) / 8, 256, 0, stream>>>(count, base, elist,
                                               alS[r], alD[r], P, outp, nd);
  }
}

// Round 8
// 849.396 us; speedup vs baseline: 1.8224x; 1.1437x over previous
//
#include <hip/hip_runtime.h>
#include <hip/hip_bf16.h>

typedef __attribute__((ext_vector_type(8))) short short8;
typedef __attribute__((ext_vector_type(4))) short short4v;
typedef __attribute__((ext_vector_type(4))) float f32x4;

__device__ __forceinline__ unsigned short f2bf(float f) {
  unsigned u = __builtin_bit_cast(unsigned, f);
  u += 0x7FFFu + ((u >> 16) & 1u);
  return (unsigned short)(u >> 16);
}
__device__ __forceinline__ float bf2f(unsigned short b) {
  unsigned u = ((unsigned)b) << 16;
  return __builtin_bit_cast(float, u);
}

// ---------------------------------------------------------------------------
// U tables: U_nodetype[j*128+k], j = r*4+h. Agent is src of r0,r2; dst of r1,r3.
__global__ void prep_u(const float* __restrict__ W, const float* __restrict__ att_src,
                       const float* __restrict__ att_dst,
                       float* __restrict__ U_agent, float* __restrict__ U_track) {
  int idx = blockIdx.x * 256 + threadIdx.x;
  if (idx >= 2 * 16 * 128) return;
  int which = idx >> 11;           // 0 agent, 1 track
  int rem = idx & 2047;
  int j = rem >> 7;                // 0..15
  int k = rem & 127;
  int r = j >> 2, h = j & 3;
  bool srcSide = (which == 0) ? ((r & 1) == 0) : ((r & 1) == 1);
  const float* att = (srcSide ? att_src : att_dst) + (r * 4 + h) * 64;
  const float* Wr = W + (r * 128 + k) * 256 + h * 64;
  float s = 0.f;
#pragma unroll 8
  for (int c = 0; c < 64; ++c) s += Wr[c] * att[c];
  (which ? U_track : U_agent)[j * 128 + k] = s;
}

// bavgT[c] = 0.5*(b0[c]+b2[c]); bavgA[c] = 0.5*(b1[c]+b3[c])
__global__ void prep_bias(const float* __restrict__ bias,
                          float* __restrict__ bavgT, float* __restrict__ bavgA) {
  int c = threadIdx.x;
  if (c < 64) bavgT[c] = 0.5f * (bias[c] + bias[128 + c]);
  else if (c < 128) bavgA[c - 64] = 0.5f * (bias[64 + c - 64] + bias[192 + c - 64]);
}

// Wt[r][c][k] = bf16(W[r][k][c])
__global__ void prep_wt(const float* __restrict__ W, unsigned short* __restrict__ Wt) {
  int idx = blockIdx.x * 256 + threadIdx.x;
  if (idx >= 4 * 256 * 128) return;
  int r = idx >> 15;
  int rem = idx & 32767;
  int c = rem >> 7;
  int k = rem & 127;
  Wt[idx] = f2bf(W[(r * 128 + k) * 256 + c]);
}

// Skinny GEMM [N x 128] @ [128 x 16]: 8 threads/node, 2 dots each, LDS-resident.
__global__ __launch_bounds__(256) void node_al2(const float* __restrict__ x,
                                                const float* __restrict__ U, int N,
                                                float* __restrict__ d0, float* __restrict__ d1,
                                                float* __restrict__ d2, float* __restrict__ d3) {
  __shared__ float xs[32 * 132];
  __shared__ float us[16 * 132];
  int tid = threadIdx.x;
  for (int i = tid; i < 2048; i += 256) us[(i >> 7) * 132 + (i & 127)] = U[i];
  int n0 = blockIdx.x * 32;
#pragma unroll
  for (int it = 0; it < 4; ++it) {
    int idx = (it * 256 + tid) * 4;
    int row = idx >> 7, k = idx & 127;
    float4 v = make_float4(0.f, 0.f, 0.f, 0.f);
    if (n0 + row < N) v = *(const float4*)(x + (size_t)(n0 + row) * 128 + k);
    *(float4*)&xs[row * 132 + k] = v;
  }
  __syncthreads();
  int node = tid >> 3;
  int g = n0 + node;
  if (g >= N) return;
  int j0 = (tid & 7) * 2;
  const float* xr = &xs[node * 132];
  const float* u0 = &us[j0 * 132];
  const float* u1 = &us[(j0 + 1) * 132];
  float a0 = 0.f, a1 = 0.f;
#pragma unroll
  for (int k = 0; k < 128; k += 4) {
    float4 xv = *(const float4*)(xr + k);
    float4 v0 = *(const float4*)(u0 + k);
    float4 v1 = *(const float4*)(u1 + k);
    a0 += xv.x * v0.x + xv.y * v0.y + xv.z * v0.z + xv.w * v0.w;
    a1 += xv.x * v1.x + xv.y * v1.y + xv.z * v1.z + xv.w * v1.w;
  }
  int r = j0 >> 2, h = j0 & 3;
  float* dp = (r == 0) ? d0 : (r == 1) ? d1 : (r == 2) ? d2 : d3;
  dp[(size_t)g * 4 + h] = a0;
  dp[(size_t)g * 4 + h + 1] = a1;
}

// P = bf16(X @ W[r]) : [Ns][256], MFMA 16x16x32 bf16
__global__ __launch_bounds__(256) void proj_gemm(const float* __restrict__ X,
                                                 const unsigned short* __restrict__ Wt,
                                                 unsigned short* __restrict__ P, int Ns) {
  __shared__ unsigned short Xs[64 * 136];
  __shared__ unsigned short Ws[128 * 136];
  int tid = threadIdx.x;
  int m0 = blockIdx.x * 64;
  int cs = blockIdx.y * 128;
#pragma unroll
  for (int it = 0; it < 8; ++it) {
    int idx = (tid + it * 256) * 4;
    int row = idx >> 7, k = idx & 127;
    int g = m0 + row;
    float4 v = make_float4(0.f, 0.f, 0.f, 0.f);
    if (g < Ns) v = *(const float4*)(X + (size_t)g * 128 + k);
    short4v sv;
    sv.x = (short)f2bf(v.x); sv.y = (short)f2bf(v.y);
    sv.z = (short)f2bf(v.z); sv.w = (short)f2bf(v.w);
    *(short4v*)&Xs[row * 136 + k] = sv;
  }
#pragma unroll
  for (int it = 0; it < 8; ++it) {
    int idx = (tid + it * 256) * 8;
    int row = idx >> 7, k = idx & 127;
    short8 v = *(const short8*)(Wt + (size_t)(cs + row) * 128 + k);
    *(short8*)&Ws[row * 136 + k] = v;
  }
  __syncthreads();
  int lane = tid & 63, w = tid >> 6;
  f32x4 acc[8];
#pragma unroll
  for (int t = 0; t < 8; ++t) acc[t] = (f32x4){0.f, 0.f, 0.f, 0.f};
  int aoff = (w * 16 + (lane & 15)) * 136 + (lane >> 4) * 8;
  int boff = (lane & 15) * 136 + (lane >> 4) * 8;
#pragma unroll
  for (int kc = 0; kc < 4; ++kc) {
    short8 a = *(const short8*)&Xs[aoff + kc * 32];
#pragma unroll
    for (int t = 0; t < 8; ++t) {
      short8 b = *(const short8*)&Ws[boff + t * 16 * 136 + kc * 32];
      acc[t] = __builtin_amdgcn_mfma_f32_16x16x32_bf16(a, b, acc[t], 0, 0, 0);
    }
  }
#pragma unroll
  for (int t = 0; t < 8; ++t) {
#pragma unroll
    for (int q = 0; q < 4; ++q) {
      int grow = m0 + w * 16 + (lane >> 4) * 4 + q;
      if (grow < Ns) P[(size_t)grow * 256 + cs + t * 16 + (lane & 15)] = f2bf(acc[t][q]);
    }
  }
}

// ---------------------- CSR build ----------------------------
__global__ void csr_hist(const int* __restrict__ edst, int* __restrict__ count, int E) {
  int e = blockIdx.x * 256 + threadIdx.x;
  if (e < E) atomicAdd(&count[edst[e]], 1);
}

// Two-segment base: segment A = [b, b+c0), segment B = [b+c0, b+c0+c2)
__global__ void csr_base2(const int* __restrict__ cntA, const int* __restrict__ cntB,
                          int* __restrict__ cursor, int* __restrict__ base,
                          int* __restrict__ fillA, int* __restrict__ fillB, int Nd) {
  int d = blockIdx.x * 256 + threadIdx.x;
  if (d >= Nd) return;
  int c0 = cntA[d], c2 = cntB[d];
  int b = atomicAdd(cursor, c0 + c2);
  base[d] = b;
  fillA[d] = b;
  fillB[d] = b + c0;
}

// scatter with a source-row offset (prow = src + rowoff)
__global__ void csr_scatter(const int* __restrict__ esrc, const int* __restrict__ edst,
                            int* __restrict__ fill, int* __restrict__ elist,
                            int rowoff, int E) {
  int e = blockIdx.x * 256 + threadIdx.x;
  if (e < E) {
    int pos = atomicAdd(&fill[edst[e]], 1);
    elist[pos] = esrc[e] + rowoff;
  }
}

// Merged two-relation pass (track dst): phase A = r0 edges, phase B = r2 edges.
// 32 lanes/dst, lane: h=l>>3, channel block (l&7)*8. Pure write out (bias folded).
__global__ __launch_bounds__(256) void passB_track(
    const int* __restrict__ cntA, const int* __restrict__ cntB,
    const int* __restrict__ base, const int* __restrict__ elist,
    const float* __restrict__ alSA, const float* __restrict__ alD0,
    const float* __restrict__ alD2, const unsigned short* __restrict__ P,
    const float* __restrict__ bavg, float* __restrict__ outp, int Nd) {
  int grp = (blockIdx.x * 256 + threadIdx.x) >> 5;
  if (grp >= Nd) return;
  int l = threadIdx.x & 31;
  int h = l >> 3;
  int loff = h * 64 + (l & 7) * 8;
  int c0 = cntA[grp], c2 = cntB[grp];
  int b = base[grp];
  float ad0 = alD0[(size_t)grp * 4 + h];
  float ad2 = alD2[(size_t)grp * 4 + h];

  float res[8];
#pragma unroll
  for (int j = 0; j < 8; ++j) res[j] = 0.f;
  float acc[8];

  // ---- phase A (r0) ----
  {
    float den = 0.f;
#pragma unroll
    for (int j = 0; j < 8; ++j) acc[j] = 0.f;
    for (int i = 0; i < c0; i += 2) {
      bool two = (i + 1 < c0);
      int s0 = elist[b + i];
      int s1 = two ? elist[b + i + 1] : s0;
      float v0 = alSA[(size_t)s0 * 4 + h] + ad0;
      float v1 = alSA[(size_t)s1 * 4 + h] + ad0;
      short8 p0 = *(const short8*)(P + (size_t)s0 * 256 + loff);
      short8 p1 = *(const short8*)(P + (size_t)s1 * 256 + loff);
      v0 = v0 > 0.f ? v0 : 0.2f * v0;
      v1 = v1 > 0.f ? v1 : 0.2f * v1;
      float e0 = __expf(v0);
      float e1 = two ? __expf(v1) : 0.f;
      den += e0 + e1;
#pragma unroll
      for (int j = 0; j < 8; ++j)
        acc[j] += e0 * bf2f((unsigned short)p0[j]) + e1 * bf2f((unsigned short)p1[j]);
    }
    float q = 0.125f / (den + 1e-16f);
#pragma unroll
    for (int j = 0; j < 8; ++j) res[j] += acc[j] * q;
  }
  // ---- phase B (r2) ----
  {
    float den = 0.f;
#pragma unroll
    for (int j = 0; j < 8; ++j) acc[j] = 0.f;
    int bb = b + c0;
    for (int i = 0; i < c2; i += 2) {
      bool two = (i + 1 < c2);
      int s0 = elist[bb + i];
      int s1 = two ? elist[bb + i + 1] : s0;
      float v0 = alSA[(size_t)s0 * 4 + h] + ad2;
      float v1 = alSA[(size_t)s1 * 4 + h] + ad2;
      short8 p0 = *(const short8*)(P + (size_t)s0 * 256 + loff);
      short8 p1 = *(const short8*)(P + (size_t)s1 * 256 + loff);
      v0 = v0 > 0.f ? v0 : 0.2f * v0;
      v1 = v1 > 0.f ? v1 : 0.2f * v1;
      float e0 = __expf(v0);
      float e1 = two ? __expf(v1) : 0.f;
      den += e0 + e1;
#pragma unroll
      for (int j = 0; j < 8; ++j)
        acc[j] += e0 * bf2f((unsigned short)p0[j]) + e1 * bf2f((unsigned short)p1[j]);
    }
    float q = 0.125f / (den + 1e-16f);
#pragma unroll
    for (int j = 0; j < 8; ++j) res[j] += acc[j] * q;
  }

#pragma unroll
  for (int j = 0; j < 8; ++j) {
    float a = res[j];
    a += __shfl_xor(a, 8);
    a += __shfl_xor(a, 16);
    res[j] = a;
  }
  if (l < 8) {
    float* op = outp + (size_t)grp * 64 + l * 8;
    const float* bv = bavg + l * 8;
    float4 c0v, c1v;
    c0v.x = bv[0] + res[0]; c0v.y = bv[1] + res[1];
    c0v.z = bv[2] + res[2]; c0v.w = bv[3] + res[3];
    c1v.x = bv[4] + res[4]; c1v.y = bv[5] + res[5];
    c1v.z = bv[6] + res[6]; c1v.w = bv[7] + res[7];
    *(float4*)op = c0v;
    *(float4*)(op + 4) = c1v;
  }
}

// Single-relation pass (agent dst). mode 0: out = bavg + res (write);
// mode 1: out += res (RMW).
__global__ __launch_bounds__(256) void passB_one(
    const int* __restrict__ count, const int* __restrict__ base,
    const int* __restrict__ elist,
    const float* __restrict__ alS, const float* __restrict__ alD,
    const unsigned short* __restrict__ P, const float* __restrict__ bavg,
    float* __restrict__ outp, int Nd, int mode) {
  int grp = (blockIdx.x * 256 + threadIdx.x) >> 5;
  if (grp >= Nd) return;
  int l = threadIdx.x & 31;
  int h = l >> 3;
  int loff = h * 64 + (l & 7) * 8;
  int cnt = count[grp];
  int b = base[grp];
  float ad = alD[(size_t)grp * 4 + h];

  float den = 0.f;
  float acc[8];
#pragma unroll
  for (int j = 0; j < 8; ++j) acc[j] = 0.f;
  for (int i = 0; i < cnt; i += 2) {
    bool two = (i + 1 < cnt);
    int s0 = elist[b + i];
    int s1 = two ? elist[b + i + 1] : s0;
    float v0 = alS[(size_t)s0 * 4 + h] + ad;
    float v1 = alS[(size_t)s1 * 4 + h] + ad;
    short8 p0 = *(const short8*)(P + (size_t)s0 * 256 + loff);
    short8 p1 = *(const short8*)(P + (size_t)s1 * 256 + loff);
    v0 = v0 > 0.f ? v0 : 0.2f * v0;
    v1 = v1 > 0.f ? v1 : 0.2f * v1;
    float e0 = __expf(v0);
    float e1 = two ? __expf(v1) : 0.f;
    den += e0 + e1;
#pragma unroll
    for (int j = 0; j < 8; ++j)
      acc[j] += e0 * bf2f((unsigned short)p0[j]) + e1 * bf2f((unsigned short)p1[j]);
  }
  float q = 0.125f / (den + 1e-16f);
#pragma unroll
  for (int j = 0; j < 8; ++j) {
    float a = acc[j] * q;
    a += __shfl_xor(a, 8);
    a += __shfl_xor(a, 16);
    acc[j] = a;
  }
  if (l < 8) {
    float* op = outp + (size_t)grp * 64 + l * 8;
    if (mode == 0) {
      const float* bv = bavg + l * 8;
      float4 c0v, c1v;
      c0v.x = bv[0] + acc[0]; c0v.y = bv[1] + acc[1];
      c0v.z = bv[2] + acc[2]; c0v.w = bv[3] + acc[3];
      c1v.x = bv[4] + acc[4]; c1v.y = bv[5] + acc[5];
      c1v.z = bv[6] + acc[6]; c1v.w = bv[7] + acc[7];
      *(float4*)op = c0v;
      *(float4*)(op + 4) = c1v;
    } else {
      float4 c0v = *(float4*)op;
      float4 c1v = *(float4*)(op + 4);
      c0v.x += acc[0]; c0v.y += acc[1]; c0v.z += acc[2]; c0v.w += acc[3];
      c1v.x += acc[4]; c1v.y += acc[5]; c1v.z += acc[6]; c1v.w += acc[7];
      *(float4*)op = c0v;
      *(float4*)(op + 4) = c1v;
    }
  }
}

extern "C" void kernel_launch(void* const* d_in, const int* in_sizes, int n_in,
                              void* d_out, int out_size, void* d_ws, size_t ws_size,
                              hipStream_t stream) {
  const float* x_agent = (const float*)d_in[0];
  const float* x_track = (const float*)d_in[1];
  const float* W = (const float*)d_in[2];
  const float* att_src = (const float*)d_in[3];
  const float* att_dst = (const float*)d_in[4];
  const float* bias = (const float*)d_in[5];
  const int* es[4] = {(const int*)d_in[6], (const int*)d_in[8],
                      (const int*)d_in[10], (const int*)d_in[12]};
  const int* ed[4] = {(const int*)d_in[7], (const int*)d_in[9],
                      (const int*)d_in[11], (const int*)d_in[13]};
  int NA = in_sizes[0] / 128;
  int NT = in_sizes[1] / 128;
  int E0 = in_sizes[6], E1 = in_sizes[8], E2 = in_sizes[10], E3 = in_sizes[12];
  float* out = (float*)d_out;
  float* out_agent = out;
  float* out_track = out + (size_t)NA * 64;

  char* ws = (char*)d_ws;
  size_t off = 0;
  auto alloc = [&](size_t bytes) -> void* {
    void* p = ws + off;
    off += (bytes + 255) & ~(size_t)255;
    return p;
  };
  int maxN = NA > NT ? NA : NT;
  int prow_max = (2 * NA > NT) ? 2 * NA : NT;          // P buffer rows
  int elist_max = E0 + E2;
  if (E1 > elist_max) elist_max = E1;
  if (E3 > elist_max) elist_max = E3;

  unsigned short* P = (unsigned short*)alloc((size_t)prow_max * 256 * 2);
  float* alSA = (float*)alloc((size_t)2 * NA * 4 * 4);   // agent src logits r0|r2
  float* alST = (float*)alloc((size_t)2 * NT * 4 * 4);   // track src logits r1|r3
  float* alD0 = (float*)alloc((size_t)NT * 4 * 4);
  float* alD1 = (float*)alloc((size_t)NA * 4 * 4);
  float* alD2 = (float*)alloc((size_t)NT * 4 * 4);
  float* alD3 = (float*)alloc((size_t)NA * 4 * 4);
  float* U_agent = (float*)alloc(16 * 128 * 4);
  float* U_track = (float*)alloc(16 * 128 * 4);
  float* bavgT = (float*)alloc(64 * 4);
  float* bavgA = (float*)alloc(64 * 4);
  unsigned short* Wt = (unsigned short*)alloc(4 * 256 * 128 * 2);
  int* ints0 = (int*)alloc(((size_t)2 * maxN + 64) * 4); // cntA | cntB | cursor
  int* cntA = ints0;
  int* cntB = ints0 + maxN;
  int* cursor = ints0 + 2 * maxN;
  int* base = (int*)alloc((size_t)maxN * 4);
  int* fillA = (int*)alloc((size_t)maxN * 4);
  int* fillB = (int*)alloc((size_t)maxN * 4);
  int* elist = (int*)alloc((size_t)elist_max * 4);

  prep_u<<<16, 256, 0, stream>>>(W, att_src, att_dst, U_agent, U_track);
  prep_bias<<<1, 128, 0, stream>>>(bias, bavgT, bavgA);
  prep_wt<<<512, 256, 0, stream>>>(W, Wt);

  // agent nodes: r0-src -> alSA[0:NA), r1-dst -> alD1, r2-src -> alSA[NA:2NA), r3-dst -> alD3
  node_al2<<<(NA + 31) / 32, 256, 0, stream>>>(x_agent, U_agent, NA,
                                               alSA, alD1, alSA + (size_t)NA * 4, alD3);
  // track nodes: r0-dst -> alD0, r1-src -> alST[0:NT), r2-dst -> alD2, r3-src -> alST[NT:2NT)
  node_al2<<<(NT + 31) / 32, 256, 0, stream>>>(x_track, U_track, NT,
                                               alD0, alST, alD2, alST + (size_t)NT * 4);

  // ---------- track dst: merged r0 + r2 ----------
  hipMemsetAsync(ints0, 0, ((size_t)2 * maxN + 64) * 4, stream);
  csr_hist<<<(E0 + 255) / 256, 256, 0, stream>>>(ed[0], cntA, E0);
  csr_hist<<<(E2 + 255) / 256, 256, 0, stream>>>(ed[2], cntB, E2);
  csr_base2<<<(NT + 255) / 256, 256, 0, stream>>>(cntA, cntB, cursor, base, fillA, fillB, NT);
  csr_scatter<<<(E0 + 255) / 256, 256, 0, stream>>>(es[0], ed[0], fillA, elist, 0, E0);
  csr_scatter<<<(E2 + 255) / 256, 256, 0, stream>>>(es[2], ed[2], fillB, elist, NA, E2);

  dim3 pgA((NA + 63) / 64, 2);
  proj_gemm<<<pgA, 256, 0, stream>>>(x_agent, Wt + 0 * 256 * 128, P, NA);
  proj_gemm<<<pgA, 256, 0, stream>>>(x_agent, Wt + (size_t)2 * 256 * 128,
                                     P + (size_t)NA * 256, NA);

  passB_track<<<(NT + 7) / 8, 256, 0, stream>>>(cntA, cntB, base, elist,
                                                alSA, alD0, alD2, P, bavgT,
                                                out_track, NT);

  // ---------- agent dst: r1 (write), r3 (RMW) ----------
  dim3 pgT((NT + 63) / 64, 2);

  hipMemsetAsync(ints0, 0, ((size_t)2 * maxN + 64) * 4, stream);
  csr_hist<<<(E1 + 255) / 256, 256, 0, stream>>>(ed[1], cntA, E1);
  csr_base2<<<(NA + 255) / 256, 256, 0, stream>>>(cntA, cntB, cursor, base, fillA, fillB, NA);
  csr_scatter<<<(E1 + 255) / 256, 256, 0, stream>>>(es[1], ed[1], fillA, elist, 0, E1);
  proj_gemm<<<pgT, 256, 0, stream>>>(x_track, Wt + (size_t)1 * 256 * 128, P, NT);
  passB_one<<<(NA + 7) / 8, 256, 0, stream>>>(cntA, base, elist, alST, alD1, P,
                                              bavgA, out_agent, NA, 0);

  hipMemsetAsync(ints0, 0, ((size_t)2 * maxN + 64) * 4, stream);
  csr_hist<<<(E3 + 255) / 256, 256, 0, stream>>>(ed[3], cntA, E3);
  csr_base2<<<(NA + 255) / 256, 256, 0, stream>>>(cntA, cntB, cursor, base, fillA, fillB, NA);
  csr_scatter<<<(E3 + 255) / 256, 256, 0, stream>>>(es[3], ed[3], fillA, elist, 0, E3);
  proj_gemm<<<pgT, 256, 0, stream>>>(x_track, Wt + (size_t)3 * 256 * 128, P, NT);
  passB_one<<<(NA + 7) / 8, 256, 0, stream>>>(cntA, base, elist,
                                              alST + (size_t)NT * 4, alD3, P,
                                              bavgA, out_agent, NA, 1);
}